// Round 10
// baseline (350.211 us; speedup 1.0000x reference)
//
#include <hip/hip_runtime.h>
#include <math.h>

typedef __attribute__((ext_vector_type(8))) short short8;      // 8 bf16 (4 VGPRs)
typedef __attribute__((ext_vector_type(4))) float floatx4;     // 4 fp32 acc

__device__ inline unsigned short f2bf(float f){
    union { float f; unsigned u; } v; v.f = f;
    unsigned r = v.u + 0x7fffu + ((v.u >> 16) & 1u);   // round-to-nearest-even
    return (unsigned short)(r >> 16);
}
__device__ inline float bf2f(unsigned short b){
    union { unsigned u; float f; } v; v.u = ((unsigned)b) << 16;
    return v.f;
}

// async global->LDS, 16B per lane, wave-uniform LDS base + lane*16
#define GLD_LDS16(g, l) __builtin_amdgcn_global_load_lds( \
    (const __attribute__((address_space(1))) void*)(g),   \
    (__attribute__((address_space(3))) void*)(l), 16, 0, 0)

// ---------------------------------------------------------------------------
// transpose helper: src [R,C] fp32 -> dst [C,R] bf16, one 32x32 tile
// ---------------------------------------------------------------------------
__device__ inline void tbody(const float* __restrict__ s,
                             unsigned short* __restrict__ d, int R, int C,
                             int c0, int r0, int t, unsigned short tile[][33]){
    int tr = t>>3, tc = (t&7)*4;
    const float* sp = s + (size_t)(r0+tr)*C + c0 + tc;
#pragma unroll
    for (int i=0;i<4;i++) tile[tr][tc+i] = f2bf(sp[i]);
    __syncthreads();
    ushort4 o; o.x = tile[tc+0][tr]; o.y = tile[tc+1][tr];
    o.z = tile[tc+2][tr]; o.w = tile[tc+3][tr];
    *(ushort4*)(d + (size_t)(c0+tr)*R + r0 + tc) = o;
}

// ---------------------------------------------------------------------------
// prep_kernel: all casts/transposes/bias-concat in ONE launch (10348 blocks)
// seg0 [0,4096): cast x -> x_bf
// seg1 [4096,5632): cast Pq|Pk|Pv -> Pbf
// seg1b [5632,6016): cast Uo -> Uo_bf (row-major, for Wo^T GEMM)
// seg2 [6016,6112): Vq/Vk/Vv [32,64] -> Vt2 [64,32] per (proj,h)
// seg3 [6112,6124): bcat
// seg4 [6124,6508): U1->U1_t   (R=1024,C=384)
// seg5 [6508,7276): Vo->Vo_t, V2->V2_t   (R=384,C=1024)
// seg6 [7276,8812): V1->V1_t             (R=384,C=4096)
// seg7 [8812,10348): U2->U2_t            (R=4096,C=384)
// ---------------------------------------------------------------------------
__global__ __launch_bounds__(256) void prep_kernel(
    const float* __restrict__ x, unsigned short* __restrict__ x_bf,
    const float* __restrict__ Pq, const float* __restrict__ Pk,
    const float* __restrict__ Pv, unsigned short* __restrict__ Pbf,
    const float* __restrict__ Uo, unsigned short* __restrict__ Uo_bf,
    const float* __restrict__ Vq, const float* __restrict__ Vk,
    const float* __restrict__ Vv, unsigned short* __restrict__ Vt2,
    const float* __restrict__ bq, const float* __restrict__ bk,
    const float* __restrict__ bv, float* __restrict__ bcat,
    const float* __restrict__ U1, unsigned short* __restrict__ U1_t,
    const float* __restrict__ Vo, unsigned short* __restrict__ Vo_t,
    const float* __restrict__ V2, unsigned short* __restrict__ V2_t,
    const float* __restrict__ V1, unsigned short* __restrict__ V1_t,
    const float* __restrict__ U2, unsigned short* __restrict__ U2_t)
{
    __shared__ unsigned short tile[32][33];
    int bid = blockIdx.x, t = threadIdx.x;
    if (bid < 4096){
        int i = (bid*256 + t)*4;
        float4 v = *(const float4*)(x+i);
        ushort4 o; o.x=f2bf(v.x); o.y=f2bf(v.y); o.z=f2bf(v.z); o.w=f2bf(v.w);
        *(ushort4*)(x_bf+i) = o;
    } else if (bid < 5632){
        int blk = bid - 4096;
        int proj = blk >> 9;
        const float* s = (proj==0)?Pq:(proj==1)?Pk:Pv;
        int off = (blk & 511)*1024 + t*4;
        float4 v = *(const float4*)(s+off);
        ushort4 o; o.x=f2bf(v.x); o.y=f2bf(v.y); o.z=f2bf(v.z); o.w=f2bf(v.w);
        *(ushort4*)(Pbf + (size_t)proj*524288 + off) = o;
    } else if (bid < 6016){
        int off = (bid - 5632)*1024 + t*4;
        float4 v = *(const float4*)(Uo+off);
        ushort4 o; o.x=f2bf(v.x); o.y=f2bf(v.y); o.z=f2bf(v.z); o.w=f2bf(v.w);
        *(ushort4*)(Uo_bf + off) = o;
    } else if (bid < 6112){
        int local = bid - 6016;
        int gx = local & 1, z = local >> 1;
        int proj = z >> 4, h = z & 15;
        const float* s = ((proj==0)?Vq:(proj==1)?Vk:Vv) + h*2048;
        unsigned short* d = Vt2 + (size_t)proj*32768 + h*2048;
        int c0 = gx*32;
        int tr = t>>3, tc = (t&7)*4;
        const float* sp = s + (size_t)tr*64 + c0 + tc;
#pragma unroll
        for (int i=0;i<4;i++) tile[tr][tc+i] = f2bf(sp[i]);
        __syncthreads();
        ushort4 o; o.x = tile[tc+0][tr]; o.y = tile[tc+1][tr];
        o.z = tile[tc+2][tr]; o.w = tile[tc+3][tr];
        *(ushort4*)(d + (size_t)(c0+tr)*32 + tc) = o;
    } else if (bid < 6124){
        int i = (bid-6112)*256 + t;
        const float* p = (i < 1024) ? bq : (i < 2048) ? bk : bv;
        bcat[i] = p[i & 1023];
    } else if (bid < 6508){
        int local = bid - 6124;
        tbody(U1, U1_t, 1024, 384, (local%12)*32, (local/12)*32, t, tile);
    } else if (bid < 7276){
        int local = bid - 6508;
        const float* s = Vo; unsigned short* d = Vo_t;
        if (local >= 384){ s = V2; d = V2_t; local -= 384; }
        tbody(s, d, 384, 1024, (local%32)*32, (local/32)*32, t, tile);
    } else if (bid < 8812){
        int local = bid - 7276;
        tbody(V1, V1_t, 384, 4096, (local%128)*32, (local/128)*32, t, tile);
    } else {
        int local = bid - 8812;
        tbody(U2, U2_t, 4096, 384, (local%12)*32, (local/12)*32, t, tile);
    }
}

// ---------------------------------------------------------------------------
// sum 4 bf16 partial planes (stride mn elems) -> bf16; 8 elems/thread
// ---------------------------------------------------------------------------
__global__ __launch_bounds__(256) void reduce4_kernel(
    const unsigned short* __restrict__ p, unsigned short* __restrict__ o, long mn){
    long i = ((long)blockIdx.x*256 + threadIdx.x)*8;
    uint4 a = *(const uint4*)(p+i);
    uint4 b = *(const uint4*)(p+mn+i);
    uint4 c = *(const uint4*)(p+2*mn+i);
    uint4 d = *(const uint4*)(p+3*mn+i);
    const unsigned short* ua = (const unsigned short*)&a;
    const unsigned short* ub = (const unsigned short*)&b;
    const unsigned short* uc = (const unsigned short*)&c;
    const unsigned short* ud = (const unsigned short*)&d;
    uint4 r; unsigned short* ur = (unsigned short*)&r;
#pragma unroll
    for (int j=0;j<8;j++)
        ur[j] = f2bf(bf2f(ua[j]) + bf2f(ub[j]) + bf2f(uc[j]) + bf2f(ud[j]));
    *(uint4*)(o+i) = r;
}

// ---------------------------------------------------------------------------
// mm64: MFMA bf16 GEMM, 64x64 tile, BK=32 (W-prep GEMMs).
// ---------------------------------------------------------------------------
__global__ __launch_bounds__(256) void mm64_kernel(
    const unsigned short* __restrict__ A, const unsigned short* __restrict__ Bt,
    unsigned short* __restrict__ C, int Kdim, int lda, int ldb, int ldc,
    long ah, long al, long bh, long bl, long ch, long cl)
{
    __shared__ unsigned short As[64*40];
    __shared__ unsigned short Bs[64*40];
    int z = blockIdx.z;
    const unsigned short* Ab = A + (size_t)(z>>4)*ah + (size_t)(z&15)*al;
    const unsigned short* Bb = Bt + (size_t)(z>>4)*bh + (size_t)(z&15)*bl;
    int row0 = blockIdx.y*64, col0 = blockIdx.x*64;
    int t = threadIdx.x;
    int ar = t>>2, ak = (t&3)*8;
    int w = t>>6, lane = t&63, quad = lane>>4, c16 = lane&15;
    int wm = (w&1)*32, wn = (w>>1)*32;

    floatx4 zero = {0.f,0.f,0.f,0.f};
    floatx4 acc[2][2];
    acc[0][0]=zero; acc[0][1]=zero; acc[1][0]=zero; acc[1][1]=zero;

    const unsigned short* Ap = Ab + (size_t)(row0+ar)*lda + ak;
    const unsigned short* Bp = Bb + (size_t)(col0+ar)*ldb + ak;

    for (int kk=0; kk<Kdim; kk+=32){
        uint4 av = *(const uint4*)(Ap + kk);
        uint4 bv = *(const uint4*)(Bp + kk);
        __syncthreads();
        *(uint4*)(As + ar*40 + ak) = av;
        *(uint4*)(Bs + ar*40 + ak) = bv;
        __syncthreads();
        short8 a0 = *(const short8*)(As + (wm   +c16)*40 + quad*8);
        short8 a1 = *(const short8*)(As + (wm+16+c16)*40 + quad*8);
        short8 b0 = *(const short8*)(Bs + (wn   +c16)*40 + quad*8);
        short8 b1 = *(const short8*)(Bs + (wn+16+c16)*40 + quad*8);
        acc[0][0] = __builtin_amdgcn_mfma_f32_16x16x32_bf16(a0,b0,acc[0][0],0,0,0);
        acc[0][1] = __builtin_amdgcn_mfma_f32_16x16x32_bf16(a0,b1,acc[0][1],0,0,0);
        acc[1][0] = __builtin_amdgcn_mfma_f32_16x16x32_bf16(a1,b0,acc[1][0],0,0,0);
        acc[1][1] = __builtin_amdgcn_mfma_f32_16x16x32_bf16(a1,b1,acc[1][1],0,0,0);
    }

    size_t zc = (size_t)(z>>4)*ch + (size_t)(z&15)*cl;
#pragma unroll
    for (int mt=0; mt<2; mt++)
#pragma unroll
    for (int r=0; r<4; r++){
        int row = row0 + wm + mt*16 + quad*4 + r;
#pragma unroll
        for (int nt=0; nt<2; nt++){
            int col = col0 + wn + nt*16 + c16;
            C[zc + (size_t)row*ldc + col] = f2bf(acc[mt][nt][r]);
        }
    }
}

// ---------------------------------------------------------------------------
// mm128: MFMA bf16 GEMM, 128x128 tile, BK=64, XOR-swizzled LDS staging.
// EPI 2: bf16 gelu(acc+aux), LDS-coalesced store
// EPI 3: f32 acc+aux+resid, direct store
// EPI 4: bf16 acc+aux scatter to QKV (Q scaled 0.125; V stored transposed),
//        LDS-coalesced (V-tile staged transposed in LDS)
// ---------------------------------------------------------------------------
template<int EPI>
__global__ __launch_bounds__(256) void mm128_kernel(
    const unsigned short* __restrict__ A, const unsigned short* __restrict__ Bt,
    void* __restrict__ C, int Kdim, int lda, int ldb, int ldc,
    const float* __restrict__ aux, const float* __restrict__ resid)
{
    __shared__ unsigned short smem[(EPI==3) ? 16384 : 17408];
    unsigned short* As = smem;
    unsigned short* Bs = smem + 8192;
    int row0 = blockIdx.y*128, col0 = blockIdx.x*128;
    int t = threadIdx.x;
    int w = t>>6, lane = t&63, quad = lane>>4, c16 = lane&15;
    int wm = (w&1)*64, wn = (w>>1)*64;

    int srow = lane>>3;                          // 0..7
    int kc = (lane&7) ^ srow;                    // swizzled source k-chunk
    const unsigned short* Ag = A + (size_t)(row0 + w*32 + srow)*lda + kc*8;
    const unsigned short* Bg = Bt + (size_t)(col0 + w*32 + srow)*ldb + kc*8;
    unsigned short* AsW = As + (w*32)*64;
    unsigned short* BsW = Bs + (w*32)*64;

    floatx4 acc[4][4];
#pragma unroll
    for (int i=0;i<4;i++)
#pragma unroll
    for (int j=0;j<4;j++) acc[i][j] = (floatx4){0.f,0.f,0.f,0.f};

    int xa = (c16&7)*8;                          // read-side XOR (elements)

    for (int kk=0; kk<Kdim; kk+=64){
#pragma unroll
        for (int i=0;i<4;i++){
            GLD_LDS16(Ag + (size_t)(i*8)*lda + kk, AsW + i*512);
            GLD_LDS16(Bg + (size_t)(i*8)*ldb + kk, BsW + i*512);
        }
        __syncthreads();
#pragma unroll
        for (int ks=0; ks<2; ks++){
            short8 a[4], b[4];
#pragma unroll
            for (int mt=0; mt<4; mt++)
                a[mt] = *(const short8*)(As + (wm + mt*16 + c16)*64
                                            + (((ks*4 + quad)*8) ^ xa));
#pragma unroll
            for (int nt=0; nt<4; nt++)
                b[nt] = *(const short8*)(Bs + (wn + nt*16 + c16)*64
                                            + (((ks*4 + quad)*8) ^ xa));
#pragma unroll
            for (int mt=0; mt<4; mt++)
#pragma unroll
                for (int nt=0; nt<4; nt++)
                    acc[mt][nt] = __builtin_amdgcn_mfma_f32_16x16x32_bf16(
                        a[mt], b[nt], acc[mt][nt], 0,0,0);
        }
        __syncthreads();
    }

    if (EPI==3){
#pragma unroll
        for (int mt=0; mt<4; mt++)
#pragma unroll
        for (int r=0; r<4; r++){
            int row = row0 + wm + mt*16 + quad*4 + r;
#pragma unroll
            for (int nt=0; nt<4; nt++){
                int col = col0 + wn + nt*16 + c16;
                ((float*)C)[(size_t)row*ldc + col] =
                    acc[mt][nt][r] + aux[col] + resid[(size_t)row*ldc + col];
            }
        }
        return;
    }

    // LDS-coalesced bf16 epilogues (EPI 2 / 4); LDS row stride 136 (16B-aligned)
    int proj = col0 >> 10;                       // only meaningful for EPI4
#pragma unroll
    for (int mt=0; mt<4; mt++)
#pragma unroll
    for (int r=0; r<4; r++){
        int row_l = wm + mt*16 + quad*4 + r;
#pragma unroll
        for (int nt=0; nt<4; nt++){
            int col_l = wn + nt*16 + c16;
            float v = acc[mt][nt][r];
            if (EPI==2){
                v += aux[col0 + col_l];
                v = 0.5f*v*(1.0f + erff(v*0.70710678118654752f));
                smem[row_l*136 + col_l] = f2bf(v);
            } else {  // EPI==4
                v += aux[col0 + col_l];
                if (proj == 0) v *= 0.125f;
                if (proj < 2) smem[row_l*136 + col_l] = f2bf(v);
                else          smem[col_l*136 + row_l] = f2bf(v);
            }
        }
    }
    __syncthreads();
    int b_ = row0 >> 9;
    int m0 = row0 & 511;
    int cbase = col0 & 1023;
#pragma unroll
    for (int i=0;i<8;i++){
        int rr = i*16 + (t>>4);
        int cc = (t&15)*8;
        uint4 val = *(const uint4*)(smem + rr*136 + cc);
        unsigned short* dst;
        if (EPI==2){
            dst = (unsigned short*)C + (size_t)(row0+rr)*ldc + col0 + cc;
        } else if (proj < 2){
            int cw = cbase + cc; int hh = cw>>6, dd = cw&63;
            dst = (unsigned short*)C + (size_t)proj*4194304
                + ((size_t)(b_*16+hh)*512 + m0 + rr)*64 + dd;
        } else {
            int cw = cbase + rr; int hh = cw>>6, dd = cw&63;
            dst = (unsigned short*)C + (size_t)2*4194304
                + ((size_t)(b_*16+hh)*64 + dd)*512 + m0 + cc;
        }
        *(uint4*)dst = val;
    }
}

// ---------------------------------------------------------------------------
// mmsk: split-K mm128 (BK=64 swizzled). bf16 partials at Cp + z*mn,
// LDS-coalesced store.
// ---------------------------------------------------------------------------
__global__ __launch_bounds__(256) void mmsk_kernel(
    const unsigned short* __restrict__ A, const unsigned short* __restrict__ Bt,
    unsigned short* __restrict__ Cp, int Kchunk, int lda, int ldb, int ldc, long mn)
{
    __shared__ unsigned short smem[17408];
    unsigned short* As = smem;
    unsigned short* Bs = smem + 8192;
    int row0 = blockIdx.y*128, col0 = blockIdx.x*128;
    int t = threadIdx.x;
    int w = t>>6, lane = t&63, quad = lane>>4, c16 = lane&15;
    int wm = (w&1)*64, wn = (w>>1)*64;

    int srow = lane>>3;
    int kc = (lane&7) ^ srow;
    const unsigned short* Ag = A + (size_t)(row0 + w*32 + srow)*lda + kc*8;
    const unsigned short* Bg = Bt + (size_t)(col0 + w*32 + srow)*ldb + kc*8;
    unsigned short* AsW = As + (w*32)*64;
    unsigned short* BsW = Bs + (w*32)*64;

    floatx4 acc[4][4];
#pragma unroll
    for (int i=0;i<4;i++)
#pragma unroll
    for (int j=0;j<4;j++) acc[i][j] = (floatx4){0.f,0.f,0.f,0.f};

    int xa = (c16&7)*8;
    int k0 = blockIdx.z * Kchunk;
    for (int kk=k0; kk<k0+Kchunk; kk+=64){
#pragma unroll
        for (int i=0;i<4;i++){
            GLD_LDS16(Ag + (size_t)(i*8)*lda + kk, AsW + i*512);
            GLD_LDS16(Bg + (size_t)(i*8)*ldb + kk, BsW + i*512);
        }
        __syncthreads();
#pragma unroll
        for (int ks=0; ks<2; ks++){
            short8 a[4], b[4];
#pragma unroll
            for (int mt=0; mt<4; mt++)
                a[mt] = *(const short8*)(As + (wm + mt*16 + c16)*64
                                            + (((ks*4 + quad)*8) ^ xa));
#pragma unroll
            for (int nt=0; nt<4; nt++)
                b[nt] = *(const short8*)(Bs + (wn + nt*16 + c16)*64
                                            + (((ks*4 + quad)*8) ^ xa));
#pragma unroll
            for (int mt=0; mt<4; mt++)
#pragma unroll
                for (int nt=0; nt<4; nt++)
                    acc[mt][nt] = __builtin_amdgcn_mfma_f32_16x16x32_bf16(
                        a[mt], b[nt], acc[mt][nt], 0,0,0);
        }
        __syncthreads();
    }

#pragma unroll
    for (int mt=0; mt<4; mt++)
#pragma unroll
    for (int r=0; r<4; r++){
        int row_l = wm + mt*16 + quad*4 + r;
#pragma unroll
        for (int nt=0; nt<4; nt++){
            int col_l = wn + nt*16 + c16;
            smem[row_l*136 + col_l] = f2bf(acc[mt][nt][r]);
        }
    }
    __syncthreads();
    unsigned short* Cz = Cp + (size_t)blockIdx.z * mn;
#pragma unroll
    for (int i=0;i<8;i++){
        int rr = i*16 + (t>>4);
        int cc = (t&15)*8;
        uint4 val = *(const uint4*)(smem + rr*136 + cc);
        *(uint4*)(Cz + (size_t)(row0+rr)*ldc + col0 + cc) = val;
    }
}

// ---------------------------------------------------------------------------
// flash_kernel: fused attention. Grid (qt=8, bh=128), 1024 blocks.
// ---------------------------------------------------------------------------
__global__ __launch_bounds__(256) void flash_kernel(
    const unsigned short* __restrict__ Qb, const unsigned short* __restrict__ Kb,
    const unsigned short* __restrict__ Vt, const float* __restrict__ mask,
    unsigned short* __restrict__ attn)
{
    __shared__ unsigned short Ks[64*64];     // [key][dh], swizzled chunks
    __shared__ unsigned short Vts[64*64];    // [dh][key], swizzled chunks
    __shared__ unsigned short Ps[4][16*64];  // per-wave P [qrow][key], swizzled

    int qt = blockIdx.x, bh = blockIdx.y;
    int b = bh >> 4, h = bh & 15;
    int t = threadIdx.x;
    int w = t>>6, lane = t&63, quad = lane>>4, c16 = lane&15;

    int qrow = qt*64 + w*16 + c16;
    const unsigned short* Qp = Qb + ((size_t)bh*512 + qrow)*64 + quad*8;
    short8 qf0 = *(const short8*)(Qp);
    short8 qf1 = *(const short8*)(Qp + 32);

    const unsigned short* Ktile0 = Kb + (size_t)bh*512*64;
    const unsigned short* Vtbh = Vt + (size_t)bh*32768;

    int srow = lane>>3;            // 0..7
    int kc = (lane&7) ^ srow;      // swizzled source chunk
    int xa = (c16&7)*8;            // read-side XOR (elements)

    floatx4 Oacc[4];
#pragma unroll
    for (int nd=0;nd<4;nd++) Oacc[nd] = (floatx4){0.f,0.f,0.f,0.f};
    float mrow[4], lrow[4];
#pragma unroll
    for (int r=0;r<4;r++){ mrow[r] = -3.0e38f; lrow[r] = 0.f; }

    unsigned short* Pw = &Ps[w][0];

    for (int kt=0; kt<8; kt++){
        __syncthreads();
#pragma unroll
        for (int i=0;i<2;i++){
            GLD_LDS16(Ktile0 + (size_t)(kt*64 + w*16 + i*8 + srow)*64 + kc*8,
                      Ks + (w*16+i*8)*64);
            GLD_LDS16(Vtbh + (size_t)(w*16 + i*8 + srow)*512 + kt*64 + kc*8,
                      Vts + (w*16+i*8)*64);
        }
        __syncthreads();

        floatx4 Sacc[4];
#pragma unroll
        for (int nt=0;nt<4;nt++){
            float mv = mask[b*512 + kt*64 + nt*16 + c16];
            Sacc[nt] = (floatx4){mv,mv,mv,mv};
        }
#pragma unroll
        for (int ks=0; ks<2; ks++){
            short8 qk = ks ? qf1 : qf0;
            short8 bfr[4];
#pragma unroll
            for (int nt=0;nt<4;nt++)
                bfr[nt] = *(const short8*)(Ks + (nt*16 + c16)*64
                                              + (((ks*4 + quad)*8) ^ xa));
#pragma unroll
            for (int nt=0;nt<4;nt++)
                Sacc[nt] = __builtin_amdgcn_mfma_f32_16x16x32_bf16(
                    qk, bfr[nt], Sacc[nt], 0,0,0);
        }

#pragma unroll
        for (int r=0;r<4;r++){
            float sv0 = Sacc[0][r], sv1 = Sacc[1][r],
                  sv2 = Sacc[2][r], sv3 = Sacc[3][r];
            float rmax = fmaxf(fmaxf(sv0,sv1), fmaxf(sv2,sv3));
            rmax = fmaxf(rmax, __shfl_xor(rmax, 1));
            rmax = fmaxf(rmax, __shfl_xor(rmax, 2));
            rmax = fmaxf(rmax, __shfl_xor(rmax, 4));
            rmax = fmaxf(rmax, __shfl_xor(rmax, 8));
            float mold = mrow[r];
            float mnew = fmaxf(mold, rmax);
            float alpha = __expf(mold - mnew);
            float p0 = __expf(sv0-mnew), p1 = __expf(sv1-mnew);
            float p2 = __expf(sv2-mnew), p3 = __expf(sv3-mnew);
            float ps = p0+p1+p2+p3;
            ps += __shfl_xor(ps, 1);
            ps += __shfl_xor(ps, 2);
            ps += __shfl_xor(ps, 4);
            ps += __shfl_xor(ps, 8);
            lrow[r] = lrow[r]*alpha + ps;
            mrow[r] = mnew;
#pragma unroll
            for (int nd=0;nd<4;nd++) Oacc[nd][r] *= alpha;
            int rl = quad*4 + r;
            int rx = rl & 7;
            int cb = rl*64 + (c16&7);
            Pw[cb + (((0*2 + (c16>>3)) ^ rx)*8)] = f2bf(p0);
            Pw[cb + (((1*2 + (c16>>3)) ^ rx)*8)] = f2bf(p1);
            Pw[cb + (((2*2 + (c16>>3)) ^ rx)*8)] = f2bf(p2);
            Pw[cb + (((3*2 + (c16>>3)) ^ rx)*8)] = f2bf(p3);
        }

#pragma unroll
        for (int ks=0; ks<2; ks++){
            short8 pa = *(const short8*)(Pw + c16*64 + (((ks*4 + quad)*8) ^ xa));
            short8 bfr[4];
#pragma unroll
            for (int nd=0;nd<4;nd++)
                bfr[nd] = *(const short8*)(Vts + (nd*16 + c16)*64
                                               + (((ks*4 + quad)*8) ^ xa));
#pragma unroll
            for (int nd=0;nd<4;nd++)
                Oacc[nd] = __builtin_amdgcn_mfma_f32_16x16x32_bf16(
                    pa, bfr[nd], Oacc[nd], 0,0,0);
        }
    }

#pragma unroll
    for (int r=0;r<4;r++){
        int m = qt*64 + w*16 + quad*4 + r;
        float inv = 1.0f / lrow[r];
        unsigned short* op = attn + ((size_t)(b*512 + m))*1024 + h*64;
#pragma unroll
        for (int nd=0;nd<4;nd++)
            op[nd*16 + c16] = f2bf(Oacc[nd][r] * inv);
    }
}

// ---------------------------------------------------------------------------
// LayerNorm over 1024 cols, fp32 in/out + optional bf16 out. 1 block/row.
// ---------------------------------------------------------------------------
template<int DUAL>
__global__ __launch_bounds__(256) void ln_kernel(
    const float* __restrict__ in, const float* __restrict__ g,
    const float* __restrict__ bta, float* __restrict__ outf,
    unsigned short* __restrict__ outb)
{
    int row = blockIdx.x;
    int t = threadIdx.x;
    const float* x = in + (size_t)row*1024;
    float4 xv = ((const float4*)x)[t];
    float s  = xv.x + xv.y + xv.z + xv.w;
    float ss = xv.x*xv.x + xv.y*xv.y + xv.z*xv.z + xv.w*xv.w;
#pragma unroll
    for (int off=32; off>0; off>>=1){ s += __shfl_down(s, off); ss += __shfl_down(ss, off); }
    __shared__ float rs[4], rss[4];
    int wid = t>>6, lane = t&63;
    if (lane==0){ rs[wid]=s; rss[wid]=ss; }
    __syncthreads();
    s  = rs[0]+rs[1]+rs[2]+rs[3];
    ss = rss[0]+rss[1]+rss[2]+rss[3];
    float mu  = s * (1.0f/1024.0f);
    float var = ss * (1.0f/1024.0f) - mu*mu;
    float inv = rsqrtf(var + 1e-12f);
    float4 gv = ((const float4*)g)[t];
    float4 bv = ((const float4*)bta)[t];
    float4 o = make_float4((xv.x-mu)*inv*gv.x+bv.x, (xv.y-mu)*inv*gv.y+bv.y,
                           (xv.z-mu)*inv*gv.z+bv.z, (xv.w-mu)*inv*gv.w+bv.w);
    ((float4*)(outf + (size_t)row*1024))[t] = o;
    if (DUAL){
        ushort4 ob; ob.x=f2bf(o.x); ob.y=f2bf(o.y); ob.z=f2bf(o.z); ob.w=f2bf(o.w);
        ((ushort4*)(outb + (size_t)row*1024))[t] = ob;
    }
}

// ---------------------------------------------------------------------------
extern "C" void kernel_launch(void* const* d_in, const int* in_sizes, int n_in,
                              void* d_out, int out_size, void* d_ws, size_t ws_size,
                              hipStream_t stream)
{
    const float* x       = (const float*)d_in[0];
    const float* mask    = (const float*)d_in[1];
    const float* Pq      = (const float*)d_in[2];
    const float* Vq      = (const float*)d_in[3];
    const float* Pk      = (const float*)d_in[4];
    const float* Vk      = (const float*)d_in[5];
    const float* Pv      = (const float*)d_in[6];
    const float* Vv      = (const float*)d_in[7];
    const float* bq      = (const float*)d_in[8];
    const float* bk      = (const float*)d_in[9];
    const float* bv      = (const float*)d_in[10];
    const float* Uo      = (const float*)d_in[11];
    const float* Vo      = (const float*)d_in[12];
    const float* bo_attn = (const float*)d_in[13];
    const float* U1      = (const float*)d_in[14];
    const float* V1      = (const float*)d_in[15];
    const float* b1      = (const float*)d_in[16];
    const float* U2      = (const float*)d_in[17];
    const float* V2      = (const float*)d_in[18];
    const float* b2      = (const float*)d_in[19];
    const float* ln1_g   = (const float*)d_in[20];
    const float* ln1_b   = (const float*)d_in[21];
    const float* ln2_g   = (const float*)d_in[22];
    const float* ln2_b   = (const float*)d_in[23];
    float* out = (float*)d_out;

    // workspace layout (byte offsets, overlaid by lifetime; R8-validated
    // layout + Wot in VIRGIN space past the R8 peak — aliases nothing, ever.
    // R1 used 121,634,816 B so ws_size >= that; Wot ends at 120,798,528.)
    char* base = (char*)d_ws;
    unsigned short* Uo_bf  = (unsigned short*)(base + 0);          // [1024,384] row-major
    unsigned short* Vo_t   = (unsigned short*)(base + 786432);     // [1024,384]
    unsigned short* U1_t   = (unsigned short*)(base + 1572864);    // [384,1024]
    unsigned short* V1_t   = (unsigned short*)(base + 2359296);    // [4096,384]
    unsigned short* U2_t   = (unsigned short*)(base + 5505024);    // [384,4096]
    unsigned short* V2_t   = (unsigned short*)(base + 8650752);    // [1024,384]
    float*          bcat   = (float*)(base + 9437184);             // [3072] f32
    unsigned short* Wt     = (unsigned short*)(base + 9449472);    // [3072,1024]
    unsigned short* Pbf    = (unsigned short*)(base + 15740928);
    unsigned short* Vt2    = (unsigned short*)(base + 18886656);
    unsigned short* x_bf   = (unsigned short*)(base + 19083264);
    unsigned short* t_bf   = (unsigned short*)(base + 9449472);    // [4096,384] (Wt dead)
    float*          ybuf   = (float*)(base + 12595200);            // [4096,1024] f32
    float*          x1     = (float*)(base + 29372416);            // [4096,1024] f32
    unsigned short* x1_bf  = (unsigned short*)(base + 46149632);   // [4096,1024]
    unsigned short* hdn_bf = (unsigned short*)(base + 54538240);   // [4096,4096]
    unsigned short* part1  = (unsigned short*)(base + 54538240);   // 4x3MB (pre-hdn)
    unsigned short* part2  = (unsigned short*)(base + 88092672);   // 4x3MB (attn bufs dead)
    unsigned short* Qb     = (unsigned short*)(base + 76558336);   // [128,512,64]
    unsigned short* Kb     = (unsigned short*)(base + 84946944);   // [128,512,64]
    unsigned short* Vt     = (unsigned short*)(base + 93535552);   // [128,64,512]
    unsigned short* attn_bf= (unsigned short*)(base + 110312768);  // [4096,1024]
    unsigned short* Wot    = (unsigned short*)(base + 118701376);  // [1024,1024] VIRGIN

    const long MN384 = 4096L*384;

    // --- all prep in one launch ---
    prep_kernel<<<10348,256,0,stream>>>(x, x_bf, Pq, Pk, Pv, Pbf, Uo, Uo_bf,
        Vq, Vk, Vv, Vt2, bq, bk, bv, bcat,
        U1, U1_t, Vo, Vo_t, V2, V2_t, V1, V1_t, U2, U2_t);

    // --- Wt[(proj,h,dh)][d] = (P_h @ V_h)^T : batched mm64, K=32 ---
    mm64_kernel<<<dim3(16,1,48),256,0,stream>>>(Vt2, Pbf, Wt,
        32, 32, 32, 1024, 32768,2048, 524288,32768, 1048576,65536);

    // --- Wot[n][k] = (Uo@Vo)^T = sum_r Vo_t[n][r] * Uo[k][r]  (mm64, K=384) ---
    mm64_kernel<<<dim3(16,16,1),256,0,stream>>>(Vo_t, Uo_bf, Wot,
        384, 384, 384, 1024, 0,0, 0,0, 0,0);

    // --- QKV = x @ W + bcat : coalesced scatter writes Q(scaled)/K/V^T ---
    mm128_kernel<4><<<dim3(24,32,1),256,0,stream>>>(x_bf, Wt, Qb,
        1024, 1024, 1024, 3072, bcat, nullptr);

    // --- fused flash attention -> heads-merged attn_bf [4096,1024] ---
    flash_kernel<<<dim3(8,128),256,0,stream>>>(Qb, Kb, Vt, mask, attn_bf);

    // --- y1 = x + attn @ Wo + bo  [4096,1024] K=1024 (fp32 out) ---
    mm128_kernel<3><<<dim3(8,32,1),256,0,stream>>>(attn_bf, Wot, ybuf,
        1024, 1024, 1024, 1024, bo_attn, x);
    ln_kernel<1><<<4096,256,0,stream>>>(ybuf, ln1_g, ln1_b, x1, x1_bf);
    // --- t1 = x1 @ U1  [4096,384] K=1024, split-K 4 (bf16 partials) ---
    mmsk_kernel<<<dim3(3,32,4),256,0,stream>>>(x1_bf, U1_t, part1,
        256, 1024, 1024, 384, MN384);
    reduce4_kernel<<<768,256,0,stream>>>(part1, t_bf, MN384);
    // --- hdn = gelu(t1 @ V1 + b1)  [4096,4096] K=384 ---
    mm128_kernel<2><<<dim3(32,32,1),256,0,stream>>>(t_bf, V1_t, hdn_bf,
        384, 384, 384, 4096, b1, nullptr);
    // --- t2 = hdn @ U2  [4096,384] K=4096, split-K 4 ---
    mmsk_kernel<<<dim3(3,32,4),256,0,stream>>>(hdn_bf, U2_t, part2,
        1024, 4096, 4096, 384, MN384);
    reduce4_kernel<<<768,256,0,stream>>>(part2, t_bf, MN384);
    // --- y2 = x1 + t2 @ V2 + b2  [4096,1024] K=384 (fp32 out) ---
    mm128_kernel<3><<<dim3(8,32,1),256,0,stream>>>(t_bf, V2_t, ybuf,
        384, 384, 384, 1024, b2, x1);
    ln_kernel<0><<<4096,256,0,stream>>>(ybuf, ln2_g, ln2_b, out, nullptr);
}

// Round 11
// 336.863 us; speedup vs baseline: 1.0396x; 1.0396x over previous
//
#include <hip/hip_runtime.h>
#include <math.h>

typedef __attribute__((ext_vector_type(8))) short short8;      // 8 bf16 (4 VGPRs)
typedef __attribute__((ext_vector_type(4))) float floatx4;     // 4 fp32 acc

__device__ inline unsigned short f2bf(float f){
    union { float f; unsigned u; } v; v.f = f;
    unsigned r = v.u + 0x7fffu + ((v.u >> 16) & 1u);   // round-to-nearest-even
    return (unsigned short)(r >> 16);
}
__device__ inline float bf2f(unsigned short b){
    union { unsigned u; float f; } v; v.u = ((unsigned)b) << 16;
    return v.f;
}

// async global->LDS, 16B per lane, wave-uniform LDS base + lane*16
#define GLD_LDS16(g, l) __builtin_amdgcn_global_load_lds( \
    (const __attribute__((address_space(1))) void*)(g),   \
    (__attribute__((address_space(3))) void*)(l), 16, 0, 0)

// ---------------------------------------------------------------------------
// transpose helper: src [R,C] fp32 -> dst [C,R] bf16, one 32x32 tile
// ---------------------------------------------------------------------------
__device__ inline void tbody(const float* __restrict__ s,
                             unsigned short* __restrict__ d, int R, int C,
                             int c0, int r0, int t, unsigned short tile[][33]){
    int tr = t>>3, tc = (t&7)*4;
    const float* sp = s + (size_t)(r0+tr)*C + c0 + tc;
#pragma unroll
    for (int i=0;i<4;i++) tile[tr][tc+i] = f2bf(sp[i]);
    __syncthreads();
    ushort4 o; o.x = tile[tc+0][tr]; o.y = tile[tc+1][tr];
    o.z = tile[tc+2][tr]; o.w = tile[tc+3][tr];
    *(ushort4*)(d + (size_t)(c0+tr)*R + r0 + tc) = o;
}

// ---------------------------------------------------------------------------
// prep_kernel: all casts/transposes/bias-concat in ONE launch (10348 blocks)
// seg0 [0,4096): cast x -> x_bf
// seg1 [4096,5632): cast Pq|Pk|Pv -> Pbf
// seg1b [5632,6016): cast Uo -> Uo_bf (unused downstream; kept for layout parity)
// seg2 [6016,6112): Vq/Vk/Vv [32,64] -> Vt2 [64,32] per (proj,h)
// seg3 [6112,6124): bcat
// seg4 [6124,6508): U1->U1_t   (R=1024,C=384)
// seg5 [6508,7276): Vo->Vo_t, V2->V2_t   (R=384,C=1024)
// seg6 [7276,8812): V1->V1_t             (R=384,C=4096)
// seg7 [8812,10348): U2->U2_t            (R=4096,C=384)
// ---------------------------------------------------------------------------
__global__ __launch_bounds__(256) void prep_kernel(
    const float* __restrict__ x, unsigned short* __restrict__ x_bf,
    const float* __restrict__ Pq, const float* __restrict__ Pk,
    const float* __restrict__ Pv, unsigned short* __restrict__ Pbf,
    const float* __restrict__ Uo, unsigned short* __restrict__ Uo_t,
    const float* __restrict__ Vq, const float* __restrict__ Vk,
    const float* __restrict__ Vv, unsigned short* __restrict__ Vt2,
    const float* __restrict__ bq, const float* __restrict__ bk,
    const float* __restrict__ bv, float* __restrict__ bcat,
    const float* __restrict__ U1, unsigned short* __restrict__ U1_t,
    const float* __restrict__ Vo, unsigned short* __restrict__ Vo_t,
    const float* __restrict__ V2, unsigned short* __restrict__ V2_t,
    const float* __restrict__ V1, unsigned short* __restrict__ V1_t,
    const float* __restrict__ U2, unsigned short* __restrict__ U2_t)
{
    __shared__ unsigned short tile[32][33];
    int bid = blockIdx.x, t = threadIdx.x;
    if (bid < 4096){
        int i = (bid*256 + t)*4;
        float4 v = *(const float4*)(x+i);
        ushort4 o; o.x=f2bf(v.x); o.y=f2bf(v.y); o.z=f2bf(v.z); o.w=f2bf(v.w);
        *(ushort4*)(x_bf+i) = o;
    } else if (bid < 5632){
        int blk = bid - 4096;
        int proj = blk >> 9;
        const float* s = (proj==0)?Pq:(proj==1)?Pk:Pv;
        int off = (blk & 511)*1024 + t*4;
        float4 v = *(const float4*)(s+off);
        ushort4 o; o.x=f2bf(v.x); o.y=f2bf(v.y); o.z=f2bf(v.z); o.w=f2bf(v.w);
        *(ushort4*)(Pbf + (size_t)proj*524288 + off) = o;
    } else if (bid < 6016){
        // Uo transpose: 384 blocks, (R=1024,C=384) -> Uo_t [384,1024]
        int local = bid - 5632;
        tbody(Uo, Uo_t, 1024, 384, (local%12)*32, (local/12)*32, t, tile);
    } else if (bid < 6112){
        int local = bid - 6016;
        int gx = local & 1, z = local >> 1;
        int proj = z >> 4, h = z & 15;
        const float* s = ((proj==0)?Vq:(proj==1)?Vk:Vv) + h*2048;
        unsigned short* d = Vt2 + (size_t)proj*32768 + h*2048;
        int c0 = gx*32;
        int tr = t>>3, tc = (t&7)*4;
        const float* sp = s + (size_t)tr*64 + c0 + tc;
#pragma unroll
        for (int i=0;i<4;i++) tile[tr][tc+i] = f2bf(sp[i]);
        __syncthreads();
        ushort4 o; o.x = tile[tc+0][tr]; o.y = tile[tc+1][tr];
        o.z = tile[tc+2][tr]; o.w = tile[tc+3][tr];
        *(ushort4*)(d + (size_t)(c0+tr)*32 + tc) = o;
    } else if (bid < 6124){
        int i = (bid-6112)*256 + t;
        const float* p = (i < 1024) ? bq : (i < 2048) ? bk : bv;
        bcat[i] = p[i & 1023];
    } else if (bid < 6508){
        int local = bid - 6124;
        tbody(U1, U1_t, 1024, 384, (local%12)*32, (local/12)*32, t, tile);
    } else if (bid < 7276){
        int local = bid - 6508;
        const float* s = Vo; unsigned short* d = Vo_t;
        if (local >= 384){ s = V2; d = V2_t; local -= 384; }
        tbody(s, d, 384, 1024, (local%32)*32, (local/32)*32, t, tile);
    } else if (bid < 8812){
        int local = bid - 7276;
        tbody(V1, V1_t, 384, 4096, (local%128)*32, (local/128)*32, t, tile);
    } else {
        int local = bid - 8812;
        tbody(U2, U2_t, 4096, 384, (local%12)*32, (local/12)*32, t, tile);
    }
}

// ---------------------------------------------------------------------------
// sum 4 bf16 partial planes (stride mn elems) -> bf16; 8 elems/thread
// ---------------------------------------------------------------------------
__global__ __launch_bounds__(256) void reduce4_kernel(
    const unsigned short* __restrict__ p, unsigned short* __restrict__ o, long mn){
    long i = ((long)blockIdx.x*256 + threadIdx.x)*8;
    uint4 a = *(const uint4*)(p+i);
    uint4 b = *(const uint4*)(p+mn+i);
    uint4 c = *(const uint4*)(p+2*mn+i);
    uint4 d = *(const uint4*)(p+3*mn+i);
    const unsigned short* ua = (const unsigned short*)&a;
    const unsigned short* ub = (const unsigned short*)&b;
    const unsigned short* uc = (const unsigned short*)&c;
    const unsigned short* ud = (const unsigned short*)&d;
    uint4 r; unsigned short* ur = (unsigned short*)&r;
#pragma unroll
    for (int j=0;j<8;j++)
        ur[j] = f2bf(bf2f(ua[j]) + bf2f(ub[j]) + bf2f(uc[j]) + bf2f(ud[j]));
    *(uint4*)(o+i) = r;
}

// ---------------------------------------------------------------------------
// mm64: MFMA bf16 GEMM, 64x64 tile, BK=32 (W-prep GEMMs).
// ---------------------------------------------------------------------------
__global__ __launch_bounds__(256) void mm64_kernel(
    const unsigned short* __restrict__ A, const unsigned short* __restrict__ Bt,
    unsigned short* __restrict__ C, int Kdim, int lda, int ldb, int ldc,
    long ah, long al, long bh, long bl, long ch, long cl)
{
    __shared__ unsigned short As[64*40];
    __shared__ unsigned short Bs[64*40];
    int z = blockIdx.z;
    const unsigned short* Ab = A + (size_t)(z>>4)*ah + (size_t)(z&15)*al;
    const unsigned short* Bb = Bt + (size_t)(z>>4)*bh + (size_t)(z&15)*bl;
    int row0 = blockIdx.y*64, col0 = blockIdx.x*64;
    int t = threadIdx.x;
    int ar = t>>2, ak = (t&3)*8;
    int w = t>>6, lane = t&63, quad = lane>>4, c16 = lane&15;
    int wm = (w&1)*32, wn = (w>>1)*32;

    floatx4 zero = {0.f,0.f,0.f,0.f};
    floatx4 acc[2][2];
    acc[0][0]=zero; acc[0][1]=zero; acc[1][0]=zero; acc[1][1]=zero;

    const unsigned short* Ap = Ab + (size_t)(row0+ar)*lda + ak;
    const unsigned short* Bp = Bb + (size_t)(col0+ar)*ldb + ak;

    for (int kk=0; kk<Kdim; kk+=32){
        uint4 av = *(const uint4*)(Ap + kk);
        uint4 bv = *(const uint4*)(Bp + kk);
        __syncthreads();
        *(uint4*)(As + ar*40 + ak) = av;
        *(uint4*)(Bs + ar*40 + ak) = bv;
        __syncthreads();
        short8 a0 = *(const short8*)(As + (wm   +c16)*40 + quad*8);
        short8 a1 = *(const short8*)(As + (wm+16+c16)*40 + quad*8);
        short8 b0 = *(const short8*)(Bs + (wn   +c16)*40 + quad*8);
        short8 b1 = *(const short8*)(Bs + (wn+16+c16)*40 + quad*8);
        acc[0][0] = __builtin_amdgcn_mfma_f32_16x16x32_bf16(a0,b0,acc[0][0],0,0,0);
        acc[0][1] = __builtin_amdgcn_mfma_f32_16x16x32_bf16(a0,b1,acc[0][1],0,0,0);
        acc[1][0] = __builtin_amdgcn_mfma_f32_16x16x32_bf16(a1,b0,acc[1][0],0,0,0);
        acc[1][1] = __builtin_amdgcn_mfma_f32_16x16x32_bf16(a1,b1,acc[1][1],0,0,0);
    }

    size_t zc = (size_t)(z>>4)*ch + (size_t)(z&15)*cl;
#pragma unroll
    for (int mt=0; mt<2; mt++)
#pragma unroll
    for (int r=0; r<4; r++){
        int row = row0 + wm + mt*16 + quad*4 + r;
#pragma unroll
        for (int nt=0; nt<2; nt++){
            int col = col0 + wn + nt*16 + c16;
            C[zc + (size_t)row*ldc + col] = f2bf(acc[mt][nt][r]);
        }
    }
}

// ---------------------------------------------------------------------------
// mm128: MFMA bf16 GEMM, 128x128 tile, BK=64, XOR-swizzled LDS staging.
// EPI 2: bf16 gelu(acc+aux), LDS-coalesced store
// EPI 3: f32 acc+aux+resid, direct store
// EPI 4: bf16 acc+aux scatter to QKV (Q scaled 0.125; V stored transposed),
//        LDS-coalesced (V-tile staged transposed in LDS)
// ---------------------------------------------------------------------------
template<int EPI>
__global__ __launch_bounds__(256) void mm128_kernel(
    const unsigned short* __restrict__ A, const unsigned short* __restrict__ Bt,
    void* __restrict__ C, int Kdim, int lda, int ldb, int ldc,
    const float* __restrict__ aux, const float* __restrict__ resid)
{
    __shared__ unsigned short smem[(EPI==3) ? 16384 : 17408];
    unsigned short* As = smem;
    unsigned short* Bs = smem + 8192;
    int row0 = blockIdx.y*128, col0 = blockIdx.x*128;
    int t = threadIdx.x;
    int w = t>>6, lane = t&63, quad = lane>>4, c16 = lane&15;
    int wm = (w&1)*64, wn = (w>>1)*64;

    int srow = lane>>3;                          // 0..7
    int kc = (lane&7) ^ srow;                    // swizzled source k-chunk
    const unsigned short* Ag = A + (size_t)(row0 + w*32 + srow)*lda + kc*8;
    const unsigned short* Bg = Bt + (size_t)(col0 + w*32 + srow)*ldb + kc*8;
    unsigned short* AsW = As + (w*32)*64;
    unsigned short* BsW = Bs + (w*32)*64;

    floatx4 acc[4][4];
#pragma unroll
    for (int i=0;i<4;i++)
#pragma unroll
    for (int j=0;j<4;j++) acc[i][j] = (floatx4){0.f,0.f,0.f,0.f};

    int xa = (c16&7)*8;                          // read-side XOR (elements)

    for (int kk=0; kk<Kdim; kk+=64){
#pragma unroll
        for (int i=0;i<4;i++){
            GLD_LDS16(Ag + (size_t)(i*8)*lda + kk, AsW + i*512);
            GLD_LDS16(Bg + (size_t)(i*8)*ldb + kk, BsW + i*512);
        }
        __syncthreads();
#pragma unroll
        for (int ks=0; ks<2; ks++){
            short8 a[4], b[4];
#pragma unroll
            for (int mt=0; mt<4; mt++)
                a[mt] = *(const short8*)(As + (wm + mt*16 + c16)*64
                                            + (((ks*4 + quad)*8) ^ xa));
#pragma unroll
            for (int nt=0; nt<4; nt++)
                b[nt] = *(const short8*)(Bs + (wn + nt*16 + c16)*64
                                            + (((ks*4 + quad)*8) ^ xa));
#pragma unroll
            for (int mt=0; mt<4; mt++)
#pragma unroll
                for (int nt=0; nt<4; nt++)
                    acc[mt][nt] = __builtin_amdgcn_mfma_f32_16x16x32_bf16(
                        a[mt], b[nt], acc[mt][nt], 0,0,0);
        }
        __syncthreads();
    }

    if (EPI==3){
#pragma unroll
        for (int mt=0; mt<4; mt++)
#pragma unroll
        for (int r=0; r<4; r++){
            int row = row0 + wm + mt*16 + quad*4 + r;
#pragma unroll
            for (int nt=0; nt<4; nt++){
                int col = col0 + wn + nt*16 + c16;
                ((float*)C)[(size_t)row*ldc + col] =
                    acc[mt][nt][r] + aux[col] + resid[(size_t)row*ldc + col];
            }
        }
        return;
    }

    // LDS-coalesced bf16 epilogues (EPI 2 / 4); LDS row stride 136 (16B-aligned)
    int proj = col0 >> 10;                       // only meaningful for EPI4
#pragma unroll
    for (int mt=0; mt<4; mt++)
#pragma unroll
    for (int r=0; r<4; r++){
        int row_l = wm + mt*16 + quad*4 + r;
#pragma unroll
        for (int nt=0; nt<4; nt++){
            int col_l = wn + nt*16 + c16;
            float v = acc[mt][nt][r];
            if (EPI==2){
                v += aux[col0 + col_l];
                v = 0.5f*v*(1.0f + erff(v*0.70710678118654752f));
                smem[row_l*136 + col_l] = f2bf(v);
            } else {  // EPI==4
                v += aux[col0 + col_l];
                if (proj == 0) v *= 0.125f;
                if (proj < 2) smem[row_l*136 + col_l] = f2bf(v);
                else          smem[col_l*136 + row_l] = f2bf(v);
            }
        }
    }
    __syncthreads();
    int b_ = row0 >> 9;
    int m0 = row0 & 511;
    int cbase = col0 & 1023;
#pragma unroll
    for (int i=0;i<8;i++){
        int rr = i*16 + (t>>4);
        int cc = (t&15)*8;
        uint4 val = *(const uint4*)(smem + rr*136 + cc);
        unsigned short* dst;
        if (EPI==2){
            dst = (unsigned short*)C + (size_t)(row0+rr)*ldc + col0 + cc;
        } else if (proj < 2){
            int cw = cbase + cc; int hh = cw>>6, dd = cw&63;
            dst = (unsigned short*)C + (size_t)proj*4194304
                + ((size_t)(b_*16+hh)*512 + m0 + rr)*64 + dd;
        } else {
            int cw = cbase + rr; int hh = cw>>6, dd = cw&63;
            dst = (unsigned short*)C + (size_t)2*4194304
                + ((size_t)(b_*16+hh)*64 + dd)*512 + m0 + cc;
        }
        *(uint4*)dst = val;
    }
}

// ---------------------------------------------------------------------------
// mmsk: split-K mm128 (BK=64 swizzled). bf16 partials at Cp + z*mn,
// LDS-coalesced store.
// ---------------------------------------------------------------------------
__global__ __launch_bounds__(256) void mmsk_kernel(
    const unsigned short* __restrict__ A, const unsigned short* __restrict__ Bt,
    unsigned short* __restrict__ Cp, int Kchunk, int lda, int ldb, int ldc, long mn)
{
    __shared__ unsigned short smem[17408];
    unsigned short* As = smem;
    unsigned short* Bs = smem + 8192;
    int row0 = blockIdx.y*128, col0 = blockIdx.x*128;
    int t = threadIdx.x;
    int w = t>>6, lane = t&63, quad = lane>>4, c16 = lane&15;
    int wm = (w&1)*64, wn = (w>>1)*64;

    int srow = lane>>3;
    int kc = (lane&7) ^ srow;
    const unsigned short* Ag = A + (size_t)(row0 + w*32 + srow)*lda + kc*8;
    const unsigned short* Bg = Bt + (size_t)(col0 + w*32 + srow)*ldb + kc*8;
    unsigned short* AsW = As + (w*32)*64;
    unsigned short* BsW = Bs + (w*32)*64;

    floatx4 acc[4][4];
#pragma unroll
    for (int i=0;i<4;i++)
#pragma unroll
    for (int j=0;j<4;j++) acc[i][j] = (floatx4){0.f,0.f,0.f,0.f};

    int xa = (c16&7)*8;
    int k0 = blockIdx.z * Kchunk;
    for (int kk=k0; kk<k0+Kchunk; kk+=64){
#pragma unroll
        for (int i=0;i<4;i++){
            GLD_LDS16(Ag + (size_t)(i*8)*lda + kk, AsW + i*512);
            GLD_LDS16(Bg + (size_t)(i*8)*ldb + kk, BsW + i*512);
        }
        __syncthreads();
#pragma unroll
        for (int ks=0; ks<2; ks++){
            short8 a[4], b[4];
#pragma unroll
            for (int mt=0; mt<4; mt++)
                a[mt] = *(const short8*)(As + (wm + mt*16 + c16)*64
                                            + (((ks*4 + quad)*8) ^ xa));
#pragma unroll
            for (int nt=0; nt<4; nt++)
                b[nt] = *(const short8*)(Bs + (wn + nt*16 + c16)*64
                                            + (((ks*4 + quad)*8) ^ xa));
#pragma unroll
            for (int mt=0; mt<4; mt++)
#pragma unroll
                for (int nt=0; nt<4; nt++)
                    acc[mt][nt] = __builtin_amdgcn_mfma_f32_16x16x32_bf16(
                        a[mt], b[nt], acc[mt][nt], 0,0,0);
        }
        __syncthreads();
    }

#pragma unroll
    for (int mt=0; mt<4; mt++)
#pragma unroll
    for (int r=0; r<4; r++){
        int row_l = wm + mt*16 + quad*4 + r;
#pragma unroll
        for (int nt=0; nt<4; nt++){
            int col_l = wn + nt*16 + c16;
            smem[row_l*136 + col_l] = f2bf(acc[mt][nt][r]);
        }
    }
    __syncthreads();
    unsigned short* Cz = Cp + (size_t)blockIdx.z * mn;
#pragma unroll
    for (int i=0;i<8;i++){
        int rr = i*16 + (t>>4);
        int cc = (t&15)*8;
        uint4 val = *(const uint4*)(smem + rr*136 + cc);
        *(uint4*)(Cz + (size_t)(row0+rr)*ldc + col0 + cc) = val;
    }
}

// ---------------------------------------------------------------------------
// flash_kernel: fused attention. Grid (bh=128, qt=8) — bh on x so all 8
// qt-blocks of one (b,h) land on the same XCD (linear id = qt*128+bh,
// XCD = id%8 = bh%8) and share K/Vt through that XCD's L2.
// ---------------------------------------------------------------------------
__global__ __launch_bounds__(256) void flash_kernel(
    const unsigned short* __restrict__ Qb, const unsigned short* __restrict__ Kb,
    const unsigned short* __restrict__ Vt, const float* __restrict__ mask,
    unsigned short* __restrict__ attn)
{
    __shared__ unsigned short Ks[64*64];     // [key][dh], swizzled chunks
    __shared__ unsigned short Vts[64*64];    // [dh][key], swizzled chunks
    __shared__ unsigned short Ps[4][16*64];  // per-wave P [qrow][key], swizzled

    int bh = blockIdx.x, qt = blockIdx.y;
    int b = bh >> 4, h = bh & 15;
    int t = threadIdx.x;
    int w = t>>6, lane = t&63, quad = lane>>4, c16 = lane&15;

    int qrow = qt*64 + w*16 + c16;
    const unsigned short* Qp = Qb + ((size_t)bh*512 + qrow)*64 + quad*8;
    short8 qf0 = *(const short8*)(Qp);
    short8 qf1 = *(const short8*)(Qp + 32);

    const unsigned short* Ktile0 = Kb + (size_t)bh*512*64;
    const unsigned short* Vtbh = Vt + (size_t)bh*32768;

    int srow = lane>>3;            // 0..7
    int kc = (lane&7) ^ srow;      // swizzled source chunk
    int xa = (c16&7)*8;            // read-side XOR (elements)

    floatx4 Oacc[4];
#pragma unroll
    for (int nd=0;nd<4;nd++) Oacc[nd] = (floatx4){0.f,0.f,0.f,0.f};
    float mrow[4], lrow[4];
#pragma unroll
    for (int r=0;r<4;r++){ mrow[r] = -3.0e38f; lrow[r] = 0.f; }

    unsigned short* Pw = &Ps[w][0];

    for (int kt=0; kt<8; kt++){
        __syncthreads();
#pragma unroll
        for (int i=0;i<2;i++){
            GLD_LDS16(Ktile0 + (size_t)(kt*64 + w*16 + i*8 + srow)*64 + kc*8,
                      Ks + (w*16+i*8)*64);
            GLD_LDS16(Vtbh + (size_t)(w*16 + i*8 + srow)*512 + kt*64 + kc*8,
                      Vts + (w*16+i*8)*64);
        }
        __syncthreads();

        floatx4 Sacc[4];
#pragma unroll
        for (int nt=0;nt<4;nt++){
            float mv = mask[b*512 + kt*64 + nt*16 + c16];
            Sacc[nt] = (floatx4){mv,mv,mv,mv};
        }
#pragma unroll
        for (int ks=0; ks<2; ks++){
            short8 qk = ks ? qf1 : qf0;
            short8 bfr[4];
#pragma unroll
            for (int nt=0;nt<4;nt++)
                bfr[nt] = *(const short8*)(Ks + (nt*16 + c16)*64
                                              + (((ks*4 + quad)*8) ^ xa));
#pragma unroll
            for (int nt=0;nt<4;nt++)
                Sacc[nt] = __builtin_amdgcn_mfma_f32_16x16x32_bf16(
                    qk, bfr[nt], Sacc[nt], 0,0,0);
        }

#pragma unroll
        for (int r=0;r<4;r++){
            float sv0 = Sacc[0][r], sv1 = Sacc[1][r],
                  sv2 = Sacc[2][r], sv3 = Sacc[3][r];
            float rmax = fmaxf(fmaxf(sv0,sv1), fmaxf(sv2,sv3));
            rmax = fmaxf(rmax, __shfl_xor(rmax, 1));
            rmax = fmaxf(rmax, __shfl_xor(rmax, 2));
            rmax = fmaxf(rmax, __shfl_xor(rmax, 4));
            rmax = fmaxf(rmax, __shfl_xor(rmax, 8));
            float mold = mrow[r];
            float mnew = fmaxf(mold, rmax);
            float alpha = __expf(mold - mnew);
            float p0 = __expf(sv0-mnew), p1 = __expf(sv1-mnew);
            float p2 = __expf(sv2-mnew), p3 = __expf(sv3-mnew);
            float ps = p0+p1+p2+p3;
            ps += __shfl_xor(ps, 1);
            ps += __shfl_xor(ps, 2);
            ps += __shfl_xor(ps, 4);
            ps += __shfl_xor(ps, 8);
            lrow[r] = lrow[r]*alpha + ps;
            mrow[r] = mnew;
#pragma unroll
            for (int nd=0;nd<4;nd++) Oacc[nd][r] *= alpha;
            int rl = quad*4 + r;
            int rx = rl & 7;
            int cb = rl*64 + (c16&7);
            Pw[cb + (((0*2 + (c16>>3)) ^ rx)*8)] = f2bf(p0);
            Pw[cb + (((1*2 + (c16>>3)) ^ rx)*8)] = f2bf(p1);
            Pw[cb + (((2*2 + (c16>>3)) ^ rx)*8)] = f2bf(p2);
            Pw[cb + (((3*2 + (c16>>3)) ^ rx)*8)] = f2bf(p3);
        }

#pragma unroll
        for (int ks=0; ks<2; ks++){
            short8 pa = *(const short8*)(Pw + c16*64 + (((ks*4 + quad)*8) ^ xa));
            short8 bfr[4];
#pragma unroll
            for (int nd=0;nd<4;nd++)
                bfr[nd] = *(const short8*)(Vts + (nd*16 + c16)*64
                                               + (((ks*4 + quad)*8) ^ xa));
#pragma unroll
            for (int nd=0;nd<4;nd++)
                Oacc[nd] = __builtin_amdgcn_mfma_f32_16x16x32_bf16(
                    pa, bfr[nd], Oacc[nd], 0,0,0);
        }
    }

#pragma unroll
    for (int r=0;r<4;r++){
        int m = qt*64 + w*16 + quad*4 + r;
        float inv = 1.0f / lrow[r];
        unsigned short* op = attn + ((size_t)(b*512 + m))*1024 + h*64;
#pragma unroll
        for (int nd=0;nd<4;nd++)
            op[nd*16 + c16] = f2bf(Oacc[nd][r] * inv);
    }
}

// ---------------------------------------------------------------------------
// LayerNorm over 1024 cols, fp32 in/out + optional bf16 out. 1 block/row.
// ---------------------------------------------------------------------------
template<int DUAL>
__global__ __launch_bounds__(256) void ln_kernel(
    const float* __restrict__ in, const float* __restrict__ g,
    const float* __restrict__ bta, float* __restrict__ outf,
    unsigned short* __restrict__ outb)
{
    int row = blockIdx.x;
    int t = threadIdx.x;
    const float* x = in + (size_t)row*1024;
    float4 xv = ((const float4*)x)[t];
    float s  = xv.x + xv.y + xv.z + xv.w;
    float ss = xv.x*xv.x + xv.y*xv.y + xv.z*xv.z + xv.w*xv.w;
#pragma unroll
    for (int off=32; off>0; off>>=1){ s += __shfl_down(s, off); ss += __shfl_down(ss, off); }
    __shared__ float rs[4], rss[4];
    int wid = t>>6, lane = t&63;
    if (lane==0){ rs[wid]=s; rss[wid]=ss; }
    __syncthreads();
    s  = rs[0]+rs[1]+rs[2]+rs[3];
    ss = rss[0]+rss[1]+rss[2]+rss[3];
    float mu  = s * (1.0f/1024.0f);
    float var = ss * (1.0f/1024.0f) - mu*mu;
    float inv = rsqrtf(var + 1e-12f);
    float4 gv = ((const float4*)g)[t];
    float4 bv = ((const float4*)bta)[t];
    float4 o = make_float4((xv.x-mu)*inv*gv.x+bv.x, (xv.y-mu)*inv*gv.y+bv.y,
                           (xv.z-mu)*inv*gv.z+bv.z, (xv.w-mu)*inv*gv.w+bv.w);
    ((float4*)(outf + (size_t)row*1024))[t] = o;
    if (DUAL){
        ushort4 ob; ob.x=f2bf(o.x); ob.y=f2bf(o.y); ob.z=f2bf(o.z); ob.w=f2bf(o.w);
        ((ushort4*)(outb + (size_t)row*1024))[t] = ob;
    }
}

// ---------------------------------------------------------------------------
extern "C" void kernel_launch(void* const* d_in, const int* in_sizes, int n_in,
                              void* d_out, int out_size, void* d_ws, size_t ws_size,
                              hipStream_t stream)
{
    const float* x       = (const float*)d_in[0];
    const float* mask    = (const float*)d_in[1];
    const float* Pq      = (const float*)d_in[2];
    const float* Vq      = (const float*)d_in[3];
    const float* Pk      = (const float*)d_in[4];
    const float* Vk      = (const float*)d_in[5];
    const float* Pv      = (const float*)d_in[6];
    const float* Vv      = (const float*)d_in[7];
    const float* bq      = (const float*)d_in[8];
    const float* bk      = (const float*)d_in[9];
    const float* bv      = (const float*)d_in[10];
    const float* Uo      = (const float*)d_in[11];
    const float* Vo      = (const float*)d_in[12];
    const float* bo_attn = (const float*)d_in[13];
    const float* U1      = (const float*)d_in[14];
    const float* V1      = (const float*)d_in[15];
    const float* b1      = (const float*)d_in[16];
    const float* U2      = (const float*)d_in[17];
    const float* V2      = (const float*)d_in[18];
    const float* b2      = (const float*)d_in[19];
    const float* ln1_g   = (const float*)d_in[20];
    const float* ln1_b   = (const float*)d_in[21];
    const float* ln2_g   = (const float*)d_in[22];
    const float* ln2_b   = (const float*)d_in[23];
    float* out = (float*)d_out;

    // workspace layout — exact R8-validated overlay
    char* base = (char*)d_ws;
    unsigned short* Uo_t   = (unsigned short*)(base + 0);          // [384,1024]
    unsigned short* Vo_t   = (unsigned short*)(base + 786432);     // [1024,384]
    unsigned short* U1_t   = (unsigned short*)(base + 1572864);    // [384,1024]
    unsigned short* V1_t   = (unsigned short*)(base + 2359296);    // [4096,384]
    unsigned short* U2_t   = (unsigned short*)(base + 5505024);    // [384,4096]
    unsigned short* V2_t   = (unsigned short*)(base + 8650752);    // [1024,384]
    float*          bcat   = (float*)(base + 9437184);             // [3072] f32
    unsigned short* Wt     = (unsigned short*)(base + 9449472);    // [3072,1024]
    unsigned short* Pbf    = (unsigned short*)(base + 15740928);
    unsigned short* Vt2    = (unsigned short*)(base + 18886656);
    unsigned short* x_bf   = (unsigned short*)(base + 19083264);
    unsigned short* t_bf   = (unsigned short*)(base + 9449472);    // [4096,384] (Wt dead)
    float*          ybuf   = (float*)(base + 12595200);            // [4096,1024] f32
    float*          x1     = (float*)(base + 29372416);            // [4096,1024] f32
    unsigned short* x1_bf  = (unsigned short*)(base + 46149632);   // [4096,1024]
    unsigned short* hdn_bf = (unsigned short*)(base + 54538240);   // [4096,4096]
    unsigned short* part0  = (unsigned short*)(base + 12595200);   // 4x3MB bf16
    unsigned short* part1  = (unsigned short*)(base + 54538240);
    unsigned short* part2  = (unsigned short*)(base + 88092672);
    unsigned short* Qb     = (unsigned short*)(base + 76558336);   // [128,512,64]
    unsigned short* Kb     = (unsigned short*)(base + 84946944);   // [128,512,64]
    unsigned short* Vt     = (unsigned short*)(base + 93535552);   // [128,64,512]
    unsigned short* attn_bf= (unsigned short*)(base + 110312768);  // [4096,1024]

    const long MN384 = 4096L*384;

    // --- all prep in one launch ---
    prep_kernel<<<10348,256,0,stream>>>(x, x_bf, Pq, Pk, Pv, Pbf, Uo, Uo_t,
        Vq, Vk, Vv, Vt2, bq, bk, bv, bcat,
        U1, U1_t, Vo, Vo_t, V2, V2_t, V1, V1_t, U2, U2_t);

    // --- Wt[(proj,h,dh)][d] = (P_h @ V_h)^T : batched mm64, K=32 ---
    mm64_kernel<<<dim3(16,1,48),256,0,stream>>>(Vt2, Pbf, Wt,
        32, 32, 32, 1024, 32768,2048, 524288,32768, 1048576,65536);

    // --- QKV = x @ W + bcat : coalesced scatter writes Q(scaled)/K/V^T ---
    mm128_kernel<4><<<dim3(24,32,1),256,0,stream>>>(x_bf, Wt, Qb,
        1024, 1024, 1024, 3072, bcat, nullptr);

    // --- fused flash attention (XCD-local grid) -> attn_bf [4096,1024] ---
    flash_kernel<<<dim3(128,8),256,0,stream>>>(Qb, Kb, Vt, mask, attn_bf);

    // --- t0 = attn @ Uo  [4096,384] K=1024, split-K 4 (bf16 partials) ---
    mmsk_kernel<<<dim3(3,32,4),256,0,stream>>>(attn_bf, Uo_t, part0,
        256, 1024, 1024, 384, MN384);
    reduce4_kernel<<<768,256,0,stream>>>(part0, t_bf, MN384);
    // --- y1 = x + t0 @ Vo + bo  [4096,1024] K=384 (fp32 out) ---
    mm128_kernel<3><<<dim3(8,32,1),256,0,stream>>>(t_bf, Vo_t, ybuf,
        384, 384, 384, 1024, bo_attn, x);
    ln_kernel<1><<<4096,256,0,stream>>>(ybuf, ln1_g, ln1_b, x1, x1_bf);
    // --- t1 = x1 @ U1  [4096,384] K=1024, split-K 4 ---
    mmsk_kernel<<<dim3(3,32,4),256,0,stream>>>(x1_bf, U1_t, part1,
        256, 1024, 1024, 384, MN384);
    reduce4_kernel<<<768,256,0,stream>>>(part1, t_bf, MN384);
    // --- hdn = gelu(t1 @ V1 + b1)  [4096,4096] K=384 ---
    mm128_kernel<2><<<dim3(32,32,1),256,0,stream>>>(t_bf, V1_t, hdn_bf,
        384, 384, 384, 4096, b1, nullptr);
    // --- t2 = hdn @ U2  [4096,384] K=4096, split-K 4 ---
    mmsk_kernel<<<dim3(3,32,4),256,0,stream>>>(hdn_bf, U2_t, part2,
        1024, 4096, 4096, 384, MN384);
    reduce4_kernel<<<768,256,0,stream>>>(part2, t_bf, MN384);
    // --- y2 = x1 + t2 @ V2 + b2  [4096,1024] K=384 (fp32 out) ---
    mm128_kernel<3><<<dim3(8,32,1),256,0,stream>>>(t_bf, V2_t, ybuf,
        384, 384, 384, 1024, b2, x1);
    ln_kernel<0><<<4096,256,0,stream>>>(ybuf, ln2_g, ln2_b, out, nullptr);
}

// Round 12
// 335.310 us; speedup vs baseline: 1.0444x; 1.0046x over previous
//
#include <hip/hip_runtime.h>
#include <math.h>

typedef __attribute__((ext_vector_type(8))) short short8;      // 8 bf16 (4 VGPRs)
typedef __attribute__((ext_vector_type(4))) float floatx4;     // 4 fp32 acc

__device__ inline unsigned short f2bf(float f){
    union { float f; unsigned u; } v; v.f = f;
    unsigned r = v.u + 0x7fffu + ((v.u >> 16) & 1u);   // round-to-nearest-even
    return (unsigned short)(r >> 16);
}
__device__ inline float bf2f(unsigned short b){
    union { unsigned u; float f; } v; v.u = ((unsigned)b) << 16;
    return v.f;
}

// async global->LDS, 16B per lane, wave-uniform LDS base + lane*16
#define GLD_LDS16(g, l) __builtin_amdgcn_global_load_lds( \
    (const __attribute__((address_space(1))) void*)(g),   \
    (__attribute__((address_space(3))) void*)(l), 16, 0, 0)

// ---------------------------------------------------------------------------
// transpose helper: src [R,C] fp32 -> dst [C,R] bf16, one 32x32 tile
// ---------------------------------------------------------------------------
__device__ inline void tbody(const float* __restrict__ s,
                             unsigned short* __restrict__ d, int R, int C,
                             int c0, int r0, int t, unsigned short tile[][33]){
    int tr = t>>3, tc = (t&7)*4;
    const float* sp = s + (size_t)(r0+tr)*C + c0 + tc;
#pragma unroll
    for (int i=0;i<4;i++) tile[tr][tc+i] = f2bf(sp[i]);
    __syncthreads();
    ushort4 o; o.x = tile[tc+0][tr]; o.y = tile[tc+1][tr];
    o.z = tile[tc+2][tr]; o.w = tile[tc+3][tr];
    *(ushort4*)(d + (size_t)(c0+tr)*R + r0 + tc) = o;
}

// ---------------------------------------------------------------------------
// prep_kernel: all casts/transposes/bias-concat in ONE launch (10348 blocks)
// ---------------------------------------------------------------------------
__global__ __launch_bounds__(256) void prep_kernel(
    const float* __restrict__ x, unsigned short* __restrict__ x_bf,
    const float* __restrict__ Pq, const float* __restrict__ Pk,
    const float* __restrict__ Pv, unsigned short* __restrict__ Pbf,
    const float* __restrict__ Uo, unsigned short* __restrict__ Uo_t,
    const float* __restrict__ Vq, const float* __restrict__ Vk,
    const float* __restrict__ Vv, unsigned short* __restrict__ Vt2,
    const float* __restrict__ bq, const float* __restrict__ bk,
    const float* __restrict__ bv, float* __restrict__ bcat,
    const float* __restrict__ U1, unsigned short* __restrict__ U1_t,
    const float* __restrict__ Vo, unsigned short* __restrict__ Vo_t,
    const float* __restrict__ V2, unsigned short* __restrict__ V2_t,
    const float* __restrict__ V1, unsigned short* __restrict__ V1_t,
    const float* __restrict__ U2, unsigned short* __restrict__ U2_t)
{
    __shared__ unsigned short tile[32][33];
    int bid = blockIdx.x, t = threadIdx.x;
    if (bid < 4096){
        int i = (bid*256 + t)*4;
        float4 v = *(const float4*)(x+i);
        ushort4 o; o.x=f2bf(v.x); o.y=f2bf(v.y); o.z=f2bf(v.z); o.w=f2bf(v.w);
        *(ushort4*)(x_bf+i) = o;
    } else if (bid < 5632){
        int blk = bid - 4096;
        int proj = blk >> 9;
        const float* s = (proj==0)?Pq:(proj==1)?Pk:Pv;
        int off = (blk & 511)*1024 + t*4;
        float4 v = *(const float4*)(s+off);
        ushort4 o; o.x=f2bf(v.x); o.y=f2bf(v.y); o.z=f2bf(v.z); o.w=f2bf(v.w);
        *(ushort4*)(Pbf + (size_t)proj*524288 + off) = o;
    } else if (bid < 6016){
        int local = bid - 5632;
        tbody(Uo, Uo_t, 1024, 384, (local%12)*32, (local/12)*32, t, tile);
    } else if (bid < 6112){
        int local = bid - 6016;
        int gx = local & 1, z = local >> 1;
        int proj = z >> 4, h = z & 15;
        const float* s = ((proj==0)?Vq:(proj==1)?Vk:Vv) + h*2048;
        unsigned short* d = Vt2 + (size_t)proj*32768 + h*2048;
        int c0 = gx*32;
        int tr = t>>3, tc = (t&7)*4;
        const float* sp = s + (size_t)tr*64 + c0 + tc;
#pragma unroll
        for (int i=0;i<4;i++) tile[tr][tc+i] = f2bf(sp[i]);
        __syncthreads();
        ushort4 o; o.x = tile[tc+0][tr]; o.y = tile[tc+1][tr];
        o.z = tile[tc+2][tr]; o.w = tile[tc+3][tr];
        *(ushort4*)(d + (size_t)(c0+tr)*32 + tc) = o;
    } else if (bid < 6124){
        int i = (bid-6112)*256 + t;
        const float* p = (i < 1024) ? bq : (i < 2048) ? bk : bv;
        bcat[i] = p[i & 1023];
    } else if (bid < 6508){
        int local = bid - 6124;
        tbody(U1, U1_t, 1024, 384, (local%12)*32, (local/12)*32, t, tile);
    } else if (bid < 7276){
        int local = bid - 6508;
        const float* s = Vo; unsigned short* d = Vo_t;
        if (local >= 384){ s = V2; d = V2_t; local -= 384; }
        tbody(s, d, 384, 1024, (local%32)*32, (local/32)*32, t, tile);
    } else if (bid < 8812){
        int local = bid - 7276;
        tbody(V1, V1_t, 384, 4096, (local%128)*32, (local/128)*32, t, tile);
    } else {
        int local = bid - 8812;
        tbody(U2, U2_t, 4096, 384, (local%12)*32, (local/12)*32, t, tile);
    }
}

// ---------------------------------------------------------------------------
// sum 4 bf16 partial planes (stride mn elems) -> bf16; 8 elems/thread
// ---------------------------------------------------------------------------
__global__ __launch_bounds__(256) void reduce4_kernel(
    const unsigned short* __restrict__ p, unsigned short* __restrict__ o, long mn){
    long i = ((long)blockIdx.x*256 + threadIdx.x)*8;
    uint4 a = *(const uint4*)(p+i);
    uint4 b = *(const uint4*)(p+mn+i);
    uint4 c = *(const uint4*)(p+2*mn+i);
    uint4 d = *(const uint4*)(p+3*mn+i);
    const unsigned short* ua = (const unsigned short*)&a;
    const unsigned short* ub = (const unsigned short*)&b;
    const unsigned short* uc = (const unsigned short*)&c;
    const unsigned short* ud = (const unsigned short*)&d;
    uint4 r; unsigned short* ur = (unsigned short*)&r;
#pragma unroll
    for (int j=0;j<8;j++)
        ur[j] = f2bf(bf2f(ua[j]) + bf2f(ub[j]) + bf2f(uc[j]) + bf2f(ud[j]));
    *(uint4*)(o+i) = r;
}

// ---------------------------------------------------------------------------
// mm64: MFMA bf16 GEMM, 64x64 tile, BK=32 (W-prep GEMM only).
// ---------------------------------------------------------------------------
__global__ __launch_bounds__(256) void mm64_kernel(
    const unsigned short* __restrict__ A, const unsigned short* __restrict__ Bt,
    unsigned short* __restrict__ C, int Kdim, int lda, int ldb, int ldc,
    long ah, long al, long bh, long bl, long ch, long cl)
{
    __shared__ unsigned short As[64*40];
    __shared__ unsigned short Bs[64*40];
    int z = blockIdx.z;
    const unsigned short* Ab = A + (size_t)(z>>4)*ah + (size_t)(z&15)*al;
    const unsigned short* Bb = Bt + (size_t)(z>>4)*bh + (size_t)(z&15)*bl;
    int row0 = blockIdx.y*64, col0 = blockIdx.x*64;
    int t = threadIdx.x;
    int ar = t>>2, ak = (t&3)*8;
    int w = t>>6, lane = t&63, quad = lane>>4, c16 = lane&15;
    int wm = (w&1)*32, wn = (w>>1)*32;

    floatx4 zero = {0.f,0.f,0.f,0.f};
    floatx4 acc[2][2];
    acc[0][0]=zero; acc[0][1]=zero; acc[1][0]=zero; acc[1][1]=zero;

    const unsigned short* Ap = Ab + (size_t)(row0+ar)*lda + ak;
    const unsigned short* Bp = Bb + (size_t)(col0+ar)*ldb + ak;

    for (int kk=0; kk<Kdim; kk+=32){
        uint4 av = *(const uint4*)(Ap + kk);
        uint4 bv = *(const uint4*)(Bp + kk);
        __syncthreads();
        *(uint4*)(As + ar*40 + ak) = av;
        *(uint4*)(Bs + ar*40 + ak) = bv;
        __syncthreads();
        short8 a0 = *(const short8*)(As + (wm   +c16)*40 + quad*8);
        short8 a1 = *(const short8*)(As + (wm+16+c16)*40 + quad*8);
        short8 b0 = *(const short8*)(Bs + (wn   +c16)*40 + quad*8);
        short8 b1 = *(const short8*)(Bs + (wn+16+c16)*40 + quad*8);
        acc[0][0] = __builtin_amdgcn_mfma_f32_16x16x32_bf16(a0,b0,acc[0][0],0,0,0);
        acc[0][1] = __builtin_amdgcn_mfma_f32_16x16x32_bf16(a0,b1,acc[0][1],0,0,0);
        acc[1][0] = __builtin_amdgcn_mfma_f32_16x16x32_bf16(a1,b0,acc[1][0],0,0,0);
        acc[1][1] = __builtin_amdgcn_mfma_f32_16x16x32_bf16(a1,b1,acc[1][1],0,0,0);
    }

    size_t zc = (size_t)(z>>4)*ch + (size_t)(z&15)*cl;
#pragma unroll
    for (int mt=0; mt<2; mt++)
#pragma unroll
    for (int r=0; r<4; r++){
        int row = row0 + wm + mt*16 + quad*4 + r;
#pragma unroll
        for (int nt=0; nt<2; nt++){
            int col = col0 + wn + nt*16 + c16;
            C[zc + (size_t)row*ldc + col] = f2bf(acc[mt][nt][r]);
        }
    }
}

// ---------------------------------------------------------------------------
// mm64g: 64x64 tile, BK=64, GLD staging + XOR swizzle (no split-K).
// For [M,384] K-heavy GEMMs: grid (N/64, M/64) keeps 384 blocks busy without
// the split-K partial round-trip. bf16 out, LDS-coalesced store.
// ---------------------------------------------------------------------------
__global__ __launch_bounds__(256) void mm64g_kernel(
    const unsigned short* __restrict__ A, const unsigned short* __restrict__ Bt,
    unsigned short* __restrict__ C, int Kdim, int lda, int ldb, int ldc)
{
    __shared__ unsigned short smem[8192];    // As 64x64 | Bs 64x64; epi 64x72
    unsigned short* As = smem;
    unsigned short* Bs = smem + 4096;
    int row0 = blockIdx.y*64, col0 = blockIdx.x*64;
    int t = threadIdx.x;
    int w = t>>6, lane = t&63, quad = lane>>4, c16 = lane&15;
    int wm = (w&1)*32, wn = (w>>1)*32;

    int srow = lane>>3;
    int kc = (lane&7) ^ srow;
    const unsigned short* Ag = A + (size_t)(row0 + w*16 + srow)*lda + kc*8;
    const unsigned short* Bg = Bt + (size_t)(col0 + w*16 + srow)*ldb + kc*8;
    unsigned short* AsW = As + (w*16)*64;
    unsigned short* BsW = Bs + (w*16)*64;

    floatx4 acc[2][2];
    acc[0][0]=acc[0][1]=acc[1][0]=acc[1][1]=(floatx4){0.f,0.f,0.f,0.f};

    int xa = (c16&7)*8;

    for (int kk=0; kk<Kdim; kk+=64){
        GLD_LDS16(Ag + kk, AsW);
        GLD_LDS16(Ag + (size_t)8*lda + kk, AsW + 512);
        GLD_LDS16(Bg + kk, BsW);
        GLD_LDS16(Bg + (size_t)8*ldb + kk, BsW + 512);
        __syncthreads();
#pragma unroll
        for (int ks=0; ks<2; ks++){
            short8 a[2], b[2];
#pragma unroll
            for (int mt=0; mt<2; mt++)
                a[mt] = *(const short8*)(As + (wm + mt*16 + c16)*64
                                            + (((ks*4 + quad)*8) ^ xa));
#pragma unroll
            for (int nt=0; nt<2; nt++)
                b[nt] = *(const short8*)(Bs + (wn + nt*16 + c16)*64
                                            + (((ks*4 + quad)*8) ^ xa));
#pragma unroll
            for (int mt=0; mt<2; mt++)
#pragma unroll
                for (int nt=0; nt<2; nt++)
                    acc[mt][nt] = __builtin_amdgcn_mfma_f32_16x16x32_bf16(
                        a[mt], b[nt], acc[mt][nt], 0,0,0);
        }
        __syncthreads();
    }

    // LDS-coalesced bf16 store, row stride 72 (144B, 16B-aligned)
#pragma unroll
    for (int mt=0; mt<2; mt++)
#pragma unroll
    for (int r=0; r<4; r++){
        int row_l = wm + mt*16 + quad*4 + r;
#pragma unroll
        for (int nt=0; nt<2; nt++){
            int col_l = wn + nt*16 + c16;
            smem[row_l*72 + col_l] = f2bf(acc[mt][nt][r]);
        }
    }
    __syncthreads();
    int rr = t>>2, cb = (t&3)*16;
    uint4 v0 = *(const uint4*)(smem + rr*72 + cb);
    uint4 v1 = *(const uint4*)(smem + rr*72 + cb + 8);
    *(uint4*)(C + (size_t)(row0+rr)*ldc + col0 + cb) = v0;
    *(uint4*)(C + (size_t)(row0+rr)*ldc + col0 + cb + 8) = v1;
}

// ---------------------------------------------------------------------------
// mm128: MFMA bf16 GEMM, 128x128 tile, BK=64, XOR-swizzled LDS staging.
// EPI 2: bf16 gelu(acc+aux), LDS-coalesced store
// EPI 3: f32 acc+aux+resid(f32), direct store
// EPI 5: f32 acc+aux+resid(bf16), direct store
// EPI 4: bf16 acc+aux scatter to QKV (Q scaled 0.125; V stored transposed)
// ---------------------------------------------------------------------------
template<int EPI>
__global__ __launch_bounds__(256) void mm128_kernel(
    const unsigned short* __restrict__ A, const unsigned short* __restrict__ Bt,
    void* __restrict__ C, int Kdim, int lda, int ldb, int ldc,
    const float* __restrict__ aux, const void* __restrict__ resid)
{
    __shared__ unsigned short smem[(EPI==3||EPI==5) ? 16384 : 17408];
    unsigned short* As = smem;
    unsigned short* Bs = smem + 8192;
    int row0 = blockIdx.y*128, col0 = blockIdx.x*128;
    int t = threadIdx.x;
    int w = t>>6, lane = t&63, quad = lane>>4, c16 = lane&15;
    int wm = (w&1)*64, wn = (w>>1)*64;

    int srow = lane>>3;                          // 0..7
    int kc = (lane&7) ^ srow;                    // swizzled source k-chunk
    const unsigned short* Ag = A + (size_t)(row0 + w*32 + srow)*lda + kc*8;
    const unsigned short* Bg = Bt + (size_t)(col0 + w*32 + srow)*ldb + kc*8;
    unsigned short* AsW = As + (w*32)*64;
    unsigned short* BsW = Bs + (w*32)*64;

    floatx4 acc[4][4];
#pragma unroll
    for (int i=0;i<4;i++)
#pragma unroll
    for (int j=0;j<4;j++) acc[i][j] = (floatx4){0.f,0.f,0.f,0.f};

    int xa = (c16&7)*8;                          // read-side XOR (elements)

    for (int kk=0; kk<Kdim; kk+=64){
#pragma unroll
        for (int i=0;i<4;i++){
            GLD_LDS16(Ag + (size_t)(i*8)*lda + kk, AsW + i*512);
            GLD_LDS16(Bg + (size_t)(i*8)*ldb + kk, BsW + i*512);
        }
        __syncthreads();
#pragma unroll
        for (int ks=0; ks<2; ks++){
            short8 a[4], b[4];
#pragma unroll
            for (int mt=0; mt<4; mt++)
                a[mt] = *(const short8*)(As + (wm + mt*16 + c16)*64
                                            + (((ks*4 + quad)*8) ^ xa));
#pragma unroll
            for (int nt=0; nt<4; nt++)
                b[nt] = *(const short8*)(Bs + (wn + nt*16 + c16)*64
                                            + (((ks*4 + quad)*8) ^ xa));
#pragma unroll
            for (int mt=0; mt<4; mt++)
#pragma unroll
                for (int nt=0; nt<4; nt++)
                    acc[mt][nt] = __builtin_amdgcn_mfma_f32_16x16x32_bf16(
                        a[mt], b[nt], acc[mt][nt], 0,0,0);
        }
        __syncthreads();
    }

    if (EPI==3 || EPI==5){
#pragma unroll
        for (int mt=0; mt<4; mt++)
#pragma unroll
        for (int r=0; r<4; r++){
            int row = row0 + wm + mt*16 + quad*4 + r;
#pragma unroll
            for (int nt=0; nt<4; nt++){
                int col = col0 + wn + nt*16 + c16;
                float rv = (EPI==3)
                    ? ((const float*)resid)[(size_t)row*ldc + col]
                    : bf2f(((const unsigned short*)resid)[(size_t)row*ldc + col]);
                ((float*)C)[(size_t)row*ldc + col] = acc[mt][nt][r] + aux[col] + rv;
            }
        }
        return;
    }

    // LDS-coalesced bf16 epilogues (EPI 2 / 4); LDS row stride 136 (16B-aligned)
    int proj = col0 >> 10;
#pragma unroll
    for (int mt=0; mt<4; mt++)
#pragma unroll
    for (int r=0; r<4; r++){
        int row_l = wm + mt*16 + quad*4 + r;
#pragma unroll
        for (int nt=0; nt<4; nt++){
            int col_l = wn + nt*16 + c16;
            float v = acc[mt][nt][r];
            if (EPI==2){
                v += aux[col0 + col_l];
                v = 0.5f*v*(1.0f + erff(v*0.70710678118654752f));
                smem[row_l*136 + col_l] = f2bf(v);
            } else {  // EPI==4
                v += aux[col0 + col_l];
                if (proj == 0) v *= 0.125f;
                if (proj < 2) smem[row_l*136 + col_l] = f2bf(v);
                else          smem[col_l*136 + row_l] = f2bf(v);
            }
        }
    }
    __syncthreads();
    int b_ = row0 >> 9;
    int m0 = row0 & 511;
    int cbase = col0 & 1023;
#pragma unroll
    for (int i=0;i<8;i++){
        int rr = i*16 + (t>>4);
        int cc = (t&15)*8;
        uint4 val = *(const uint4*)(smem + rr*136 + cc);
        unsigned short* dst;
        if (EPI==2){
            dst = (unsigned short*)C + (size_t)(row0+rr)*ldc + col0 + cc;
        } else if (proj < 2){
            int cw = cbase + cc; int hh = cw>>6, dd = cw&63;
            dst = (unsigned short*)C + (size_t)proj*4194304
                + ((size_t)(b_*16+hh)*512 + m0 + rr)*64 + dd;
        } else {
            int cw = cbase + rr; int hh = cw>>6, dd = cw&63;
            dst = (unsigned short*)C + (size_t)2*4194304
                + ((size_t)(b_*16+hh)*64 + dd)*512 + m0 + cc;
        }
        *(uint4*)dst = val;
    }
}

// ---------------------------------------------------------------------------
// mmsk: split-K mm128 (BK=64 swizzled). bf16 partials at Cp + z*mn.
// ---------------------------------------------------------------------------
__global__ __launch_bounds__(256) void mmsk_kernel(
    const unsigned short* __restrict__ A, const unsigned short* __restrict__ Bt,
    unsigned short* __restrict__ Cp, int Kchunk, int lda, int ldb, int ldc, long mn)
{
    __shared__ unsigned short smem[17408];
    unsigned short* As = smem;
    unsigned short* Bs = smem + 8192;
    int row0 = blockIdx.y*128, col0 = blockIdx.x*128;
    int t = threadIdx.x;
    int w = t>>6, lane = t&63, quad = lane>>4, c16 = lane&15;
    int wm = (w&1)*64, wn = (w>>1)*64;

    int srow = lane>>3;
    int kc = (lane&7) ^ srow;
    const unsigned short* Ag = A + (size_t)(row0 + w*32 + srow)*lda + kc*8;
    const unsigned short* Bg = Bt + (size_t)(col0 + w*32 + srow)*ldb + kc*8;
    unsigned short* AsW = As + (w*32)*64;
    unsigned short* BsW = Bs + (w*32)*64;

    floatx4 acc[4][4];
#pragma unroll
    for (int i=0;i<4;i++)
#pragma unroll
    for (int j=0;j<4;j++) acc[i][j] = (floatx4){0.f,0.f,0.f,0.f};

    int xa = (c16&7)*8;
    int k0 = blockIdx.z * Kchunk;
    for (int kk=k0; kk<k0+Kchunk; kk+=64){
#pragma unroll
        for (int i=0;i<4;i++){
            GLD_LDS16(Ag + (size_t)(i*8)*lda + kk, AsW + i*512);
            GLD_LDS16(Bg + (size_t)(i*8)*ldb + kk, BsW + i*512);
        }
        __syncthreads();
#pragma unroll
        for (int ks=0; ks<2; ks++){
            short8 a[4], b[4];
#pragma unroll
            for (int mt=0; mt<4; mt++)
                a[mt] = *(const short8*)(As + (wm + mt*16 + c16)*64
                                            + (((ks*4 + quad)*8) ^ xa));
#pragma unroll
            for (int nt=0; nt<4; nt++)
                b[nt] = *(const short8*)(Bs + (wn + nt*16 + c16)*64
                                            + (((ks*4 + quad)*8) ^ xa));
#pragma unroll
            for (int mt=0; mt<4; mt++)
#pragma unroll
                for (int nt=0; nt<4; nt++)
                    acc[mt][nt] = __builtin_amdgcn_mfma_f32_16x16x32_bf16(
                        a[mt], b[nt], acc[mt][nt], 0,0,0);
        }
        __syncthreads();
    }

#pragma unroll
    for (int mt=0; mt<4; mt++)
#pragma unroll
    for (int r=0; r<4; r++){
        int row_l = wm + mt*16 + quad*4 + r;
#pragma unroll
        for (int nt=0; nt<4; nt++){
            int col_l = wn + nt*16 + c16;
            smem[row_l*136 + col_l] = f2bf(acc[mt][nt][r]);
        }
    }
    __syncthreads();
    unsigned short* Cz = Cp + (size_t)blockIdx.z * mn;
#pragma unroll
    for (int i=0;i<8;i++){
        int rr = i*16 + (t>>4);
        int cc = (t&15)*8;
        uint4 val = *(const uint4*)(smem + rr*136 + cc);
        *(uint4*)(Cz + (size_t)(row0+rr)*ldc + col0 + cc) = val;
    }
}

// ---------------------------------------------------------------------------
// flash_kernel: fused attention. Grid (bh=128, qt=8) — XCD-local K/Vt reuse.
// ---------------------------------------------------------------------------
__global__ __launch_bounds__(256) void flash_kernel(
    const unsigned short* __restrict__ Qb, const unsigned short* __restrict__ Kb,
    const unsigned short* __restrict__ Vt, const float* __restrict__ mask,
    unsigned short* __restrict__ attn)
{
    __shared__ unsigned short Ks[64*64];
    __shared__ unsigned short Vts[64*64];
    __shared__ unsigned short Ps[4][16*64];

    int bh = blockIdx.x, qt = blockIdx.y;
    int b = bh >> 4, h = bh & 15;
    int t = threadIdx.x;
    int w = t>>6, lane = t&63, quad = lane>>4, c16 = lane&15;

    int qrow = qt*64 + w*16 + c16;
    const unsigned short* Qp = Qb + ((size_t)bh*512 + qrow)*64 + quad*8;
    short8 qf0 = *(const short8*)(Qp);
    short8 qf1 = *(const short8*)(Qp + 32);

    const unsigned short* Ktile0 = Kb + (size_t)bh*512*64;
    const unsigned short* Vtbh = Vt + (size_t)bh*32768;

    int srow = lane>>3;
    int kc = (lane&7) ^ srow;
    int xa = (c16&7)*8;

    floatx4 Oacc[4];
#pragma unroll
    for (int nd=0;nd<4;nd++) Oacc[nd] = (floatx4){0.f,0.f,0.f,0.f};
    float mrow[4], lrow[4];
#pragma unroll
    for (int r=0;r<4;r++){ mrow[r] = -3.0e38f; lrow[r] = 0.f; }

    unsigned short* Pw = &Ps[w][0];

    for (int kt=0; kt<8; kt++){
        __syncthreads();
#pragma unroll
        for (int i=0;i<2;i++){
            GLD_LDS16(Ktile0 + (size_t)(kt*64 + w*16 + i*8 + srow)*64 + kc*8,
                      Ks + (w*16+i*8)*64);
            GLD_LDS16(Vtbh + (size_t)(w*16 + i*8 + srow)*512 + kt*64 + kc*8,
                      Vts + (w*16+i*8)*64);
        }
        __syncthreads();

        floatx4 Sacc[4];
#pragma unroll
        for (int nt=0;nt<4;nt++){
            float mv = mask[b*512 + kt*64 + nt*16 + c16];
            Sacc[nt] = (floatx4){mv,mv,mv,mv};
        }
#pragma unroll
        for (int ks=0; ks<2; ks++){
            short8 qk = ks ? qf1 : qf0;
            short8 bfr[4];
#pragma unroll
            for (int nt=0;nt<4;nt++)
                bfr[nt] = *(const short8*)(Ks + (nt*16 + c16)*64
                                              + (((ks*4 + quad)*8) ^ xa));
#pragma unroll
            for (int nt=0;nt<4;nt++)
                Sacc[nt] = __builtin_amdgcn_mfma_f32_16x16x32_bf16(
                    qk, bfr[nt], Sacc[nt], 0,0,0);
        }

#pragma unroll
        for (int r=0;r<4;r++){
            float sv0 = Sacc[0][r], sv1 = Sacc[1][r],
                  sv2 = Sacc[2][r], sv3 = Sacc[3][r];
            float rmax = fmaxf(fmaxf(sv0,sv1), fmaxf(sv2,sv3));
            rmax = fmaxf(rmax, __shfl_xor(rmax, 1));
            rmax = fmaxf(rmax, __shfl_xor(rmax, 2));
            rmax = fmaxf(rmax, __shfl_xor(rmax, 4));
            rmax = fmaxf(rmax, __shfl_xor(rmax, 8));
            float mold = mrow[r];
            float mnew = fmaxf(mold, rmax);
            float alpha = __expf(mold - mnew);
            float p0 = __expf(sv0-mnew), p1 = __expf(sv1-mnew);
            float p2 = __expf(sv2-mnew), p3 = __expf(sv3-mnew);
            float ps = p0+p1+p2+p3;
            ps += __shfl_xor(ps, 1);
            ps += __shfl_xor(ps, 2);
            ps += __shfl_xor(ps, 4);
            ps += __shfl_xor(ps, 8);
            lrow[r] = lrow[r]*alpha + ps;
            mrow[r] = mnew;
#pragma unroll
            for (int nd=0;nd<4;nd++) Oacc[nd][r] *= alpha;
            int rl = quad*4 + r;
            int rx = rl & 7;
            int cb = rl*64 + (c16&7);
            Pw[cb + (((0*2 + (c16>>3)) ^ rx)*8)] = f2bf(p0);
            Pw[cb + (((1*2 + (c16>>3)) ^ rx)*8)] = f2bf(p1);
            Pw[cb + (((2*2 + (c16>>3)) ^ rx)*8)] = f2bf(p2);
            Pw[cb + (((3*2 + (c16>>3)) ^ rx)*8)] = f2bf(p3);
        }

#pragma unroll
        for (int ks=0; ks<2; ks++){
            short8 pa = *(const short8*)(Pw + c16*64 + (((ks*4 + quad)*8) ^ xa));
            short8 bfr[4];
#pragma unroll
            for (int nd=0;nd<4;nd++)
                bfr[nd] = *(const short8*)(Vts + (nd*16 + c16)*64
                                               + (((ks*4 + quad)*8) ^ xa));
#pragma unroll
            for (int nd=0;nd<4;nd++)
                Oacc[nd] = __builtin_amdgcn_mfma_f32_16x16x32_bf16(
                    pa, bfr[nd], Oacc[nd], 0,0,0);
        }
    }

#pragma unroll
    for (int r=0;r<4;r++){
        int m = qt*64 + w*16 + quad*4 + r;
        float inv = 1.0f / lrow[r];
        unsigned short* op = attn + ((size_t)(b*512 + m))*1024 + h*64;
#pragma unroll
        for (int nd=0;nd<4;nd++)
            op[nd*16 + c16] = f2bf(Oacc[nd][r] * inv);
    }
}

// ---------------------------------------------------------------------------
// LayerNorm over 1024 cols. DUAL=0: f32 out only; DUAL=2: bf16 out only.
// ---------------------------------------------------------------------------
template<int DUAL>
__global__ __launch_bounds__(256) void ln_kernel(
    const float* __restrict__ in, const float* __restrict__ g,
    const float* __restrict__ bta, float* __restrict__ outf,
    unsigned short* __restrict__ outb)
{
    int row = blockIdx.x;
    int t = threadIdx.x;
    const float* x = in + (size_t)row*1024;
    float4 xv = ((const float4*)x)[t];
    float s  = xv.x + xv.y + xv.z + xv.w;
    float ss = xv.x*xv.x + xv.y*xv.y + xv.z*xv.z + xv.w*xv.w;
#pragma unroll
    for (int off=32; off>0; off>>=1){ s += __shfl_down(s, off); ss += __shfl_down(ss, off); }
    __shared__ float rs[4], rss[4];
    int wid = t>>6, lane = t&63;
    if (lane==0){ rs[wid]=s; rss[wid]=ss; }
    __syncthreads();
    s  = rs[0]+rs[1]+rs[2]+rs[3];
    ss = rss[0]+rss[1]+rss[2]+rss[3];
    float mu  = s * (1.0f/1024.0f);
    float var = ss * (1.0f/1024.0f) - mu*mu;
    float inv = rsqrtf(var + 1e-12f);
    float4 gv = ((const float4*)g)[t];
    float4 bv = ((const float4*)bta)[t];
    float4 o = make_float4((xv.x-mu)*inv*gv.x+bv.x, (xv.y-mu)*inv*gv.y+bv.y,
                           (xv.z-mu)*inv*gv.z+bv.z, (xv.w-mu)*inv*gv.w+bv.w);
    if (DUAL != 2)
        ((float4*)(outf + (size_t)row*1024))[t] = o;
    if (DUAL){
        ushort4 ob; ob.x=f2bf(o.x); ob.y=f2bf(o.y); ob.z=f2bf(o.z); ob.w=f2bf(o.w);
        ((ushort4*)(outb + (size_t)row*1024))[t] = ob;
    }
}

// ---------------------------------------------------------------------------
extern "C" void kernel_launch(void* const* d_in, const int* in_sizes, int n_in,
                              void* d_out, int out_size, void* d_ws, size_t ws_size,
                              hipStream_t stream)
{
    const float* x       = (const float*)d_in[0];
    const float* mask    = (const float*)d_in[1];
    const float* Pq      = (const float*)d_in[2];
    const float* Vq      = (const float*)d_in[3];
    const float* Pk      = (const float*)d_in[4];
    const float* Vk      = (const float*)d_in[5];
    const float* Pv      = (const float*)d_in[6];
    const float* Vv      = (const float*)d_in[7];
    const float* bq      = (const float*)d_in[8];
    const float* bk      = (const float*)d_in[9];
    const float* bv      = (const float*)d_in[10];
    const float* Uo      = (const float*)d_in[11];
    const float* Vo      = (const float*)d_in[12];
    const float* bo_attn = (const float*)d_in[13];
    const float* U1      = (const float*)d_in[14];
    const float* V1      = (const float*)d_in[15];
    const float* b1      = (const float*)d_in[16];
    const float* U2      = (const float*)d_in[17];
    const float* V2      = (const float*)d_in[18];
    const float* b2      = (const float*)d_in[19];
    const float* ln1_g   = (const float*)d_in[20];
    const float* ln1_b   = (const float*)d_in[21];
    const float* ln2_g   = (const float*)d_in[22];
    const float* ln2_b   = (const float*)d_in[23];
    float* out = (float*)d_out;

    // workspace layout — exact R8-validated overlay (x1 f32 slot now unused)
    char* base = (char*)d_ws;
    unsigned short* Uo_t   = (unsigned short*)(base + 0);          // [384,1024]
    unsigned short* Vo_t   = (unsigned short*)(base + 786432);     // [1024,384]
    unsigned short* U1_t   = (unsigned short*)(base + 1572864);    // [384,1024]
    unsigned short* V1_t   = (unsigned short*)(base + 2359296);    // [4096,384]
    unsigned short* U2_t   = (unsigned short*)(base + 5505024);    // [384,4096]
    unsigned short* V2_t   = (unsigned short*)(base + 8650752);    // [1024,384]
    float*          bcat   = (float*)(base + 9437184);             // [3072] f32
    unsigned short* Wt     = (unsigned short*)(base + 9449472);    // [3072,1024]
    unsigned short* Pbf    = (unsigned short*)(base + 15740928);
    unsigned short* Vt2    = (unsigned short*)(base + 18886656);
    unsigned short* x_bf   = (unsigned short*)(base + 19083264);
    unsigned short* t_bf   = (unsigned short*)(base + 9449472);    // [4096,384] (Wt dead)
    float*          ybuf   = (float*)(base + 12595200);            // [4096,1024] f32
    unsigned short* x1_bf  = (unsigned short*)(base + 46149632);   // [4096,1024]
    unsigned short* hdn_bf = (unsigned short*)(base + 54538240);   // [4096,4096]
    unsigned short* part2  = (unsigned short*)(base + 88092672);   // 4x3MB bf16
    unsigned short* Qb     = (unsigned short*)(base + 76558336);   // [128,512,64]
    unsigned short* Kb     = (unsigned short*)(base + 84946944);   // [128,512,64]
    unsigned short* Vt     = (unsigned short*)(base + 93535552);   // [128,64,512]
    unsigned short* attn_bf= (unsigned short*)(base + 110312768);  // [4096,1024]

    const long MN384 = 4096L*384;

    // --- all prep in one launch ---
    prep_kernel<<<10348,256,0,stream>>>(x, x_bf, Pq, Pk, Pv, Pbf, Uo, Uo_t,
        Vq, Vk, Vv, Vt2, bq, bk, bv, bcat,
        U1, U1_t, Vo, Vo_t, V2, V2_t, V1, V1_t, U2, U2_t);

    // --- Wt[(proj,h,dh)][d] = (P_h @ V_h)^T : batched mm64, K=32 ---
    mm64_kernel<<<dim3(16,1,48),256,0,stream>>>(Vt2, Pbf, Wt,
        32, 32, 32, 1024, 32768,2048, 524288,32768, 1048576,65536);

    // --- QKV = x @ W + bcat : coalesced scatter writes Q(scaled)/K/V^T ---
    mm128_kernel<4><<<dim3(24,32,1),256,0,stream>>>(x_bf, Wt, Qb,
        1024, 1024, 1024, 3072, bcat, nullptr);

    // --- fused flash attention (XCD-local grid) -> attn_bf [4096,1024] ---
    flash_kernel<<<dim3(128,8),256,0,stream>>>(Qb, Kb, Vt, mask, attn_bf);

    // --- t0 = attn @ Uo  [4096,384] K=1024, direct 64-tile (no split-K) ---
    mm64g_kernel<<<dim3(6,64),256,0,stream>>>(attn_bf, Uo_t, t_bf,
        1024, 1024, 1024, 384);
    // --- y1 = x + t0 @ Vo + bo  [4096,1024] K=384 (fp32 out) ---
    mm128_kernel<3><<<dim3(8,32,1),256,0,stream>>>(t_bf, Vo_t, ybuf,
        384, 384, 384, 1024, bo_attn, x);
    ln_kernel<2><<<4096,256,0,stream>>>(ybuf, ln1_g, ln1_b, nullptr, x1_bf);
    // --- t1 = x1 @ U1  [4096,384] K=1024, direct 64-tile ---
    mm64g_kernel<<<dim3(6,64),256,0,stream>>>(x1_bf, U1_t, t_bf,
        1024, 1024, 1024, 384);
    // --- hdn = gelu(t1 @ V1 + b1)  [4096,4096] K=384 ---
    mm128_kernel<2><<<dim3(32,32,1),256,0,stream>>>(t_bf, V1_t, hdn_bf,
        384, 384, 384, 4096, b1, nullptr);
    // --- t2 = hdn @ U2  [4096,384] K=4096, split-K 4 ---
    mmsk_kernel<<<dim3(3,32,4),256,0,stream>>>(hdn_bf, U2_t, part2,
        1024, 4096, 4096, 384, MN384);
    reduce4_kernel<<<768,256,0,stream>>>(part2, t_bf, MN384);
    // --- y2 = x1 + t2 @ V2 + b2  [4096,1024] K=384 (fp32 out, bf16 resid) ---
    mm128_kernel<5><<<dim3(8,32,1),256,0,stream>>>(t_bf, V2_t, ybuf,
        384, 384, 384, 1024, b2, x1_bf);
    ln_kernel<0><<<4096,256,0,stream>>>(ybuf, ln2_g, ln2_b, out, nullptr);
}